// Round 7
// baseline (1449.473 us; speedup 1.0000x reference)
//
#include <hip/hip_runtime.h>
#include <hip/hip_bf16.h>
#include <math.h>

#define Bb 16
#define Nn 512
#define Dd 256
#define Hh 8
#define HD 32
#define Ll 3
#define INDIM 768
#define Ee 4096
#define FF 1024
#define MT 256   // attention m-tile
#define STP 260  // KT/srow pitch (pad 4): b128-aligned, conflict-free reads

__device__ __forceinline__ float gelu_exact(float x) {
    return 0.5f * x * (1.0f + erff(x * 0.70710678118654752f));
}

// ---------------- edge bucketing ----------------

__global__ __launch_bounds__(256) void zero_kernel(int* __restrict__ p, int n) {
    int gid = blockIdx.x * 256 + threadIdx.x;
    if (gid < n) p[gid] = 0;
}

__global__ __launch_bounds__(256) void count_kernel(const int* __restrict__ edge_index,
                                                    int* __restrict__ counts) {
    int gid = blockIdx.x * 256 + threadIdx.x; // B*E = 65536
    int b = gid >> 12;
    int e = gid & (Ee - 1);
    int src = edge_index[b * 2 * Ee + e];
    atomicAdd(&counts[b * Nn + src], 1);
}

__global__ __launch_bounds__(1024) void scan_kernel(const int* __restrict__ counts,
                                                    int* __restrict__ offsets,
                                                    int* __restrict__ cursor) {
    __shared__ int ssum[1024];
    int t = threadIdx.x;
    int local[8];
    int s = 0;
#pragma unroll
    for (int i = 0; i < 8; i++) { local[i] = counts[t * 8 + i]; s += local[i]; }
    ssum[t] = s;
    __syncthreads();
    for (int off = 1; off < 1024; off *= 2) {
        __syncthreads();
        int v = (t >= off) ? ssum[t - off] : 0;
        __syncthreads();
        ssum[t] += v;
    }
    __syncthreads();
    int base = (t > 0) ? ssum[t - 1] : 0;
#pragma unroll
    for (int i = 0; i < 8; i++) {
        offsets[t * 8 + i] = base;
        cursor[t * 8 + i] = base;
        base += local[i];
    }
    if (t == 1023) offsets[8192] = base;
}

__global__ __launch_bounds__(256) void scatter_kernel(const int* __restrict__ edge_index,
                                                      int* __restrict__ cursor,
                                                      int* __restrict__ elist) {
    int gid = blockIdx.x * 256 + threadIdx.x;
    int b = gid >> 12;
    int e = gid & (Ee - 1);
    int src = edge_index[b * 2 * Ee + e];
    int pos = atomicAdd(&cursor[b * Nn + src], 1);
    elist[pos] = gid;
}

// ---------------- fp32 GEMM A: 128x128 tile, BK=16, 8x8/thread (R5 version) ----------------

__global__ __launch_bounds__(256) void gemm128(const float* __restrict__ A,
                                               const float* __restrict__ W,
                                               const float* __restrict__ bias,
                                               float* __restrict__ C,
                                               int M, int K, int N, int act) {
    __shared__ float sA[16][128];  // [k][m]
    __shared__ float sB[16][128];  // [k][n]
    int t = threadIdx.x;
    int tx = t & 15, ty = t >> 4;
    int row0 = blockIdx.y * 128, col0 = blockIdx.x * 128;
    float acc[8][8] = {};
    int ar = t >> 1, ak = (t & 1) * 8;
    int bk = t >> 4, bc = (t & 15) * 8;

    const float* Ap = &A[(size_t)(row0 + ar) * K + ak];
    const float* Wp = &W[(size_t)bk * N + col0 + bc];

    float4 a0 = *(const float4*)&Ap[0];
    float4 a1 = *(const float4*)&Ap[4];
    float4 b0 = *(const float4*)&Wp[0];
    float4 b1 = *(const float4*)&Wp[4];

    for (int k0 = 0; k0 < K; k0 += 16) {
        __syncthreads();
        sA[ak + 0][ar] = a0.x; sA[ak + 1][ar] = a0.y;
        sA[ak + 2][ar] = a0.z; sA[ak + 3][ar] = a0.w;
        sA[ak + 4][ar] = a1.x; sA[ak + 5][ar] = a1.y;
        sA[ak + 6][ar] = a1.z; sA[ak + 7][ar] = a1.w;
        *(float4*)&sB[bk][bc] = b0;
        *(float4*)&sB[bk][bc + 4] = b1;
        __syncthreads();
        if (k0 + 16 < K) {
            a0 = *(const float4*)&Ap[k0 + 16];
            a1 = *(const float4*)&Ap[k0 + 20];
            b0 = *(const float4*)&Wp[(size_t)(k0 + 16) * N];
            b1 = *(const float4*)&Wp[(size_t)(k0 + 16) * N + 4];
        }
#pragma unroll
        for (int kk = 0; kk < 16; kk++) {
            float4 av0 = *(const float4*)&sA[kk][ty * 4];
            float4 av1 = *(const float4*)&sA[kk][64 + ty * 4];
            float4 bv0 = *(const float4*)&sB[kk][tx * 4];
            float4 bv1 = *(const float4*)&sB[kk][64 + tx * 4];
            float a[8] = {av0.x, av0.y, av0.z, av0.w, av1.x, av1.y, av1.z, av1.w};
            float bb[8] = {bv0.x, bv0.y, bv0.z, bv0.w, bv1.x, bv1.y, bv1.z, bv1.w};
#pragma unroll
            for (int i = 0; i < 8; i++)
#pragma unroll
                for (int j = 0; j < 8; j++) acc[i][j] += a[i] * bb[j];
        }
    }
#pragma unroll
    for (int i = 0; i < 8; i++) {
        int r = row0 + ((i < 4) ? (ty * 4 + i) : (64 + ty * 4 + i - 4));
#pragma unroll
        for (int jh = 0; jh < 2; jh++) {
            int c0 = col0 + jh * 64 + tx * 4;
            float4 v;
            float* vv = (float*)&v;
#pragma unroll
            for (int j = 0; j < 4; j++) {
                float u = acc[i][jh * 4 + j] + bias[c0 + j];
                if (act == 1) u = gelu_exact(u);
                vv[j] = u;
            }
            *(float4*)&C[(size_t)r * N + c0] = v;
        }
    }
}

// ---------------- fp32 GEMM B: 128x64 tile, BK=16, 8x4/thread (R5 version) ----------------

__global__ __launch_bounds__(256) void gemm128x64(const float* __restrict__ A,
                                                  const float* __restrict__ W,
                                                  const float* __restrict__ bias,
                                                  float* __restrict__ C,
                                                  int M, int K, int N, int act) {
    __shared__ float sA[16][128];  // [k][m]
    __shared__ float sB[16][64];   // [k][n]
    int t = threadIdx.x;
    int tx = t & 15, ty = t >> 4;
    int row0 = blockIdx.y * 128, col0 = blockIdx.x * 64;
    float acc[8][4] = {};
    int ar = t >> 1, ak = (t & 1) * 8;
    int bk = t >> 2, bc = (t & 3) * 16;  // unused variant guard
    bk = t >> 4; bc = (t & 15) * 4;

    const float* Ap = &A[(size_t)(row0 + ar) * K + ak];
    const float* Wp = &W[(size_t)bk * N + col0 + bc];

    float4 a0 = *(const float4*)&Ap[0];
    float4 a1 = *(const float4*)&Ap[4];
    float4 b0 = *(const float4*)&Wp[0];

    for (int k0 = 0; k0 < K; k0 += 16) {
        __syncthreads();
        sA[ak + 0][ar] = a0.x; sA[ak + 1][ar] = a0.y;
        sA[ak + 2][ar] = a0.z; sA[ak + 3][ar] = a0.w;
        sA[ak + 4][ar] = a1.x; sA[ak + 5][ar] = a1.y;
        sA[ak + 6][ar] = a1.z; sA[ak + 7][ar] = a1.w;
        *(float4*)&sB[bk][bc] = b0;
        __syncthreads();
        if (k0 + 16 < K) {
            a0 = *(const float4*)&Ap[k0 + 16];
            a1 = *(const float4*)&Ap[k0 + 20];
            b0 = *(const float4*)&Wp[(size_t)(k0 + 16) * N];
        }
#pragma unroll
        for (int kk = 0; kk < 16; kk++) {
            float4 av0 = *(const float4*)&sA[kk][ty * 4];
            float4 av1 = *(const float4*)&sA[kk][64 + ty * 4];
            float4 bv = *(const float4*)&sB[kk][tx * 4];
            float a[8] = {av0.x, av0.y, av0.z, av0.w, av1.x, av1.y, av1.z, av1.w};
            float bb[4] = {bv.x, bv.y, bv.z, bv.w};
#pragma unroll
            for (int i = 0; i < 8; i++)
#pragma unroll
                for (int j = 0; j < 4; j++) acc[i][j] += a[i] * bb[j];
        }
    }
#pragma unroll
    for (int i = 0; i < 8; i++) {
        int r = row0 + ((i < 4) ? (ty * 4 + i) : (64 + ty * 4 + i - 4));
        int c0 = col0 + tx * 4;
        float4 v;
        float* vv = (float*)&v;
#pragma unroll
        for (int j = 0; j < 4; j++) {
            float u = acc[i][j] + bias[c0 + j];
            if (act == 1) u = gelu_exact(u);
            vv[j] = u;
        }
        *(float4*)&C[(size_t)r * N + c0] = v;
    }
}

// ---------------- attention v5: m-tiled (2x256) online softmax, 2 blocks/CU ----------------
// Block per (b,h,half): 512 threads, 8 waves; wave owns 32 q-rows (8 groups of 4).
// Lane L owns tile-local m in {4L..4L+3}. KT holds one 256-m tile (restaged between
// passes); per-row running (max, expsum) in LDS scratch; PV partials in VGPRs.

__global__ __launch_bounds__(512, 4) void attn_kernel(const float* __restrict__ qkv,
                                                      const int* __restrict__ node_mask,
                                                      const int* __restrict__ offsets,
                                                      const int* __restrict__ elist,
                                                      const int* __restrict__ edge_index,
                                                      const int* __restrict__ edge_type,
                                                      const float* __restrict__ edge_weight,
                                                      const float* __restrict__ et_emb,
                                                      float* __restrict__ outbuf) {
    int bid = blockIdx.x;          // b*16 + h*2 + half
    int half = bid & 1;
    int h = (bid >> 1) & 7;
    int b = bid >> 4;
    int t = threadIdx.x;
    int w = t >> 6;   // wave 0..7
    int L = t & 63;   // lane

    __shared__ __align__(16) float KT[HD][STP];       // 33.3 KB (one m-tile)
    __shared__ __align__(16) float srow[8][4][STP];   // 33.3 KB (per-wave tile rows)
    __shared__ float mstate[8][8][4];                 // running row max
    __shared__ float lstate[8][8][4];                 // running row expsum

    const float scale = 0.17677669529663687f;  // 1/sqrt(32)
    int base = half * 256;
    int m4 = 4 * L;
    int d = L & 31, h2 = L >> 5;

    float oacc[8][4];  // tile-0 PV partials (per group, per row, this lane's (d,h2) slot)

    for (int T = 0; T < 2; T++) {
        // ---- stage KT for tile T ----
        if (T == 1) __syncthreads();  // all waves done reading tile-0 KT
        for (int i = t; i < MT * HD; i += 512) {
            int m = i >> 5, dd = i & 31;
            KT[dd][m] = qkv[(size_t)(b * Nn + T * MT + m) * 768 + 256 + h * HD + dd];
        }
        __syncthreads();

        // mask for owned tile-local m
        int4 nm = *(const int4*)&node_mask[b * Nn + T * MT + m4];
        float mb[4];
        mb[0] = nm.x ? 0.0f : -INFINITY;
        mb[1] = nm.y ? 0.0f : -INFINITY;
        mb[2] = nm.z ? 0.0f : -INFINITY;
        mb[3] = nm.w ? 0.0f : -INFINITY;

        for (int g = 0; g < 8; g++) {
            int n0 = base + w * 32 + g * 4;

            // q in registers: lane (L&31) holds q[n0+r][L&31]; broadcast via shuffle
            float qr[4];
#pragma unroll
            for (int r = 0; r < 4; r++)
                qr[r] = qkv[(size_t)(b * Nn + n0 + r) * 768 + h * HD + (L & 31)] * scale;

            // QK^T over this tile
            float s0a[4], s1a[4], s2a[4], s3a[4];
#pragma unroll
            for (int j = 0; j < 4; j++) { s0a[j] = 0.f; s1a[j] = 0.f; s2a[j] = 0.f; s3a[j] = 0.f; }
#pragma unroll 4
            for (int dd = 0; dd < HD; dd++) {
                float4 kv = *(const float4*)&KT[dd][m4];
                float kk[4] = {kv.x, kv.y, kv.z, kv.w};
                float q0 = __shfl(qr[0], dd);
                float q1 = __shfl(qr[1], dd);
                float q2 = __shfl(qr[2], dd);
                float q3 = __shfl(qr[3], dd);
#pragma unroll
                for (int j = 0; j < 4; j++) {
                    s0a[j] += q0 * kk[j];
                    s1a[j] += q1 * kk[j];
                    s2a[j] += q2 * kk[j];
                    s3a[j] += q3 * kk[j];
                }
            }
            *(float4*)&srow[w][0][m4] = make_float4(s0a[0], s0a[1], s0a[2], s0a[3]);
            *(float4*)&srow[w][1][m4] = make_float4(s1a[0], s1a[1], s1a[2], s1a[3]);
            *(float4*)&srow[w][2][m4] = make_float4(s2a[0], s2a[1], s2a[2], s2a[3]);
            *(float4*)&srow[w][3][m4] = make_float4(s3a[0], s3a[1], s3a[2], s3a[3]);

            // edge bias replay: only edges whose dst falls in this tile
            int beg = offsets[b * Nn + n0];
            int end = offsets[b * Nn + n0 + 4];
            int tlo = T * MT, thi = T * MT + MT;
            for (int i = beg + L; i < end; i += 64) {
                int ge = elist[i];
                int e = ge & (Ee - 1);
                int dst = edge_index[b * 2 * Ee + Ee + e];
                if (dst >= tlo && dst < thi) {
                    int src = edge_index[b * 2 * Ee + e];
                    int ty = edge_type[b * Ee + e];
                    float wgt = edge_weight[b * Ee + e];
                    float val = et_emb[ty * Hh + h] + (ty == 2 ? wgt : 0.0f);
                    atomicAdd(&srow[w][src - n0][dst - tlo], val);
                }
            }
            asm volatile("s_waitcnt lgkmcnt(0)" ::: "memory");

            // read back + mask + tile softmax stats; write p = exp(s - M) back
            float alpha[4], linv_or_l[4];
#pragma unroll
            for (int r = 0; r < 4; r++) {
                float4 sv = *(const float4*)&srow[w][r][m4];
                float s[4] = {sv.x + mb[0], sv.y + mb[1], sv.z + mb[2], sv.w + mb[3]};
                float mx = fmaxf(fmaxf(s[0], s[1]), fmaxf(s[2], s[3]));
#pragma unroll
                for (int o = 1; o < 64; o <<= 1) mx = fmaxf(mx, __shfl_xor(mx, o));
                float M, l0;
                if (T == 0) {
                    M = mx;
                    alpha[r] = 1.0f;
                    l0 = 0.0f;
                } else {
                    float m0 = mstate[w][g][r];
                    M = fmaxf(m0, mx);
                    alpha[r] = __expf(m0 - M);
                    l0 = lstate[w][g][r];
                }
                float sum = 0.0f;
#pragma unroll
                for (int j = 0; j < 4; j++) {
                    s[j] = __expf(s[j] - M);
                    sum += s[j];
                }
#pragma unroll
                for (int o = 1; o < 64; o <<= 1) sum += __shfl_xor(sum, o);
                float l = l0 * alpha[r] + sum;
                if (T == 0) {
                    mstate[w][g][r] = M;
                    lstate[w][g][r] = l;
                } else {
                    linv_or_l[r] = 1.0f / l;
                }
                *(float4*)&srow[w][r][m4] = make_float4(s[0], s[1], s[2], s[3]);
            }
            asm volatile("s_waitcnt lgkmcnt(0)" ::: "memory");

            // PV over this tile: lane = (d, h2); h2 selects 128-m sub-range
            const float* vp = qkv + (size_t)(b * Nn + T * MT + h2 * 128) * 768 + 512 + h * HD + d;
            float o0 = 0.0f, o1 = 0.0f, o2 = 0.0f, o3 = 0.0f;
            int mbase = h2 * 128;
#pragma unroll 2
            for (int mc = 0; mc < 128; mc += 8) {
                float v[8];
#pragma unroll
                for (int u = 0; u < 8; u++) v[u] = vp[(size_t)(mc + u) * 768];
#pragma unroll
                for (int p = 0; p < 2; p++) {
                    float4 sp0 = *(const float4*)&srow[w][0][mbase + mc + p * 4];
                    float4 sp1 = *(const float4*)&srow[w][1][mbase + mc + p * 4];
                    float4 sp2 = *(const float4*)&srow[w][2][mbase + mc + p * 4];
                    float4 sp3 = *(const float4*)&srow[w][3][mbase + mc + p * 4];
                    float* vb = &v[p * 4];
                    o0 += sp0.x * vb[0] + sp0.y * vb[1] + sp0.z * vb[2] + sp0.w * vb[3];
                    o1 += sp1.x * vb[0] + sp1.y * vb[1] + sp1.z * vb[2] + sp1.w * vb[3];
                    o2 += sp2.x * vb[0] + sp2.y * vb[1] + sp2.z * vb[2] + sp2.w * vb[3];
                    o3 += sp3.x * vb[0] + sp3.y * vb[1] + sp3.z * vb[2] + sp3.w * vb[3];
                }
            }

            if (T == 0) {
                oacc[g][0] = o0; oacc[g][1] = o1; oacc[g][2] = o2; oacc[g][3] = o3;
            } else {
                float of0 = oacc[g][0] * alpha[0] + o0;
                float of1 = oacc[g][1] * alpha[1] + o1;
                float of2 = oacc[g][2] * alpha[2] + o2;
                float of3 = oacc[g][3] * alpha[3] + o3;
                of0 += __shfl_xor(of0, 32);
                of1 += __shfl_xor(of1, 32);
                of2 += __shfl_xor(of2, 32);
                of3 += __shfl_xor(of3, 32);
                if (h2 == 0) {
                    outbuf[(size_t)(b * Nn + n0 + 0) * Dd + h * HD + d] = of0 * linv_or_l[0];
                    outbuf[(size_t)(b * Nn + n0 + 1) * Dd + h * HD + d] = of1 * linv_or_l[1];
                    outbuf[(size_t)(b * Nn + n0 + 2) * Dd + h * HD + d] = of2 * linv_or_l[2];
                    outbuf[(size_t)(b * Nn + n0 + 3) * Dd + h * HD + d] = of3 * linv_or_l[3];
                }
            }
        }
    }
}

// ---------------- residual + LayerNorm ----------------

__global__ __launch_bounds__(256) void ln_kernel(float* __restrict__ x,
                                                 const float* __restrict__ res,
                                                 const float* __restrict__ g,
                                                 const float* __restrict__ bta) {
    int row = blockIdx.x;
    int t = threadIdx.x;
    __shared__ float red[4];
    __shared__ float stats[2];
    size_t idx = (size_t)row * Dd + t;
    float v = x[idx] + res[idx];
    float sm = v;
    for (int o = 32; o > 0; o >>= 1) sm += __shfl_down(sm, o);
    if ((t & 63) == 0) red[t >> 6] = sm;
    __syncthreads();
    if (t == 0) stats[0] = (red[0] + red[1] + red[2] + red[3]) * (1.0f / Dd);
    __syncthreads();
    float mu = stats[0];
    float dv = v - mu;
    float s2 = dv * dv;
    for (int o = 32; o > 0; o >>= 1) s2 += __shfl_down(s2, o);
    if ((t & 63) == 0) red[t >> 6] = s2;
    __syncthreads();
    if (t == 0) stats[1] = 1.0f / sqrtf((red[0] + red[1] + red[2] + red[3]) * (1.0f / Dd) + 1e-5f);
    __syncthreads();
    x[idx] = dv * stats[1] * g[t] + bta[t];
}

// ---------------- head ----------------

__global__ __launch_bounds__(256) void pool_kernel(const float* __restrict__ x,
                                                   const int* __restrict__ text_mask,
                                                   const int* __restrict__ image_mask,
                                                   float* __restrict__ pools) {
    int b = blockIdx.y;
    int n0 = blockIdx.x * 32;
    int t = threadIdx.x;
    float tp = 0.0f, ip = 0.0f, c1 = 0.0f, c2 = 0.0f;
    for (int n = n0; n < n0 + 32; n++) {
        float xv = x[(size_t)(b * Nn + n) * Dd + t];
        int tm = text_mask[b * Nn + n];
        int im = image_mask[b * Nn + n];
        tp += tm ? xv : 0.0f;
        ip += im ? xv : 0.0f;
        c1 += (float)tm;
        c2 += (float)im;
    }
    atomicAdd(&pools[b * 514 + t], tp);
    atomicAdd(&pools[b * 514 + 256 + t], ip);
    if (t == 0) {
        atomicAdd(&pools[b * 514 + 512], c1);
        atomicAdd(&pools[b * 514 + 513], c2);
    }
}

__global__ __launch_bounds__(256) void comb_kernel(const float* __restrict__ x,
                                                   const float* __restrict__ pools,
                                                   const int* __restrict__ gidx,
                                                   float* __restrict__ comb) {
    int b = blockIdx.x;
    int t = threadIdx.x;
    __shared__ float redd[12];
    float tc = fmaxf(pools[b * 514 + 512], 1.0f);
    float ic = fmaxf(pools[b * 514 + 513], 1.0f);
    float tp = pools[b * 514 + t] / tc;
    float ip = pools[b * 514 + 256 + t] / ic;
    int gi = gidx[b];
    comb[b * 776 + t] = x[(size_t)(b * Nn + gi) * Dd + t];
    comb[b * 776 + 256 + t] = tp;
    comb[b * 776 + 512 + t] = ip;
    float dotv = tp * ip, n1v = tp * tp, n2v = ip * ip;
    for (int o = 32; o > 0; o >>= 1) {
        dotv += __shfl_down(dotv, o);
        n1v += __shfl_down(n1v, o);
        n2v += __shfl_down(n2v, o);
    }
    if ((t & 63) == 0) { redd[t >> 6] = dotv; redd[4 + (t >> 6)] = n1v; redd[8 + (t >> 6)] = n2v; }
    __syncthreads();
    if (t == 0) {
        float dd = redd[0] + redd[1] + redd[2] + redd[3];
        float a1 = fmaxf(sqrtf(redd[4] + redd[5] + redd[6] + redd[7]), 1e-6f);
        float a2 = fmaxf(sqrtf(redd[8] + redd[9] + redd[10] + redd[11]), 1e-6f);
        comb[b * 776 + 768] = 1.0f - dd / (a1 * a2);
    }
}

__global__ __launch_bounds__(256) void h1_kernel(const float* __restrict__ comb,
                                                 const float* __restrict__ Wm1,
                                                 const float* __restrict__ bm1,
                                                 float* __restrict__ h1) {
    int b = blockIdx.y;
    int jc = blockIdx.x;
    int t = threadIdx.x;
    __shared__ float scomb[776];
    __shared__ float partial[2][128];
    for (int i = t; i < 769; i += 256) scomb[i] = comb[b * 776 + i];
    __syncthreads();
    int j = jc * 128 + (t & 127);
    int kh = t >> 7;
    int kbeg = kh ? 384 : 0;
    int kend = kh ? 769 : 384;
    float acc = 0.0f;
#pragma unroll 8
    for (int k = kbeg; k < kend; k++) acc += scomb[k] * Wm1[k * 512 + j];
    partial[kh][t & 127] = acc;
    __syncthreads();
    if (t < 128) {
        float v = partial[0][t] + partial[1][t] + bm1[jc * 128 + t];
        h1[b * 512 + jc * 128 + t] = gelu_exact(v);
    }
}

__global__ __launch_bounds__(256) void head_fin(const float* __restrict__ h1,
                                                const float* __restrict__ Wm2,
                                                const float* __restrict__ bm2,
                                                const float* __restrict__ Wm3,
                                                const float* __restrict__ bm3,
                                                float* __restrict__ out) {
    int b = blockIdx.x;
    int t = threadIdx.x;
    __shared__ float h1s[512];
    __shared__ float red[4];
    for (int i = t; i < 512; i += 256) h1s[i] = h1[b * 512 + i];
    __syncthreads();
    float acc = bm2[t];
#pragma unroll 8
    for (int k = 0; k < 512; k++) acc += h1s[k] * Wm2[k * 256 + t];
    float h2 = gelu_exact(acc);
    float lv = h2 * Wm3[t];
    for (int o = 32; o > 0; o >>= 1) lv += __shfl_down(lv, o);
    if ((t & 63) == 0) red[t >> 6] = lv;
    __syncthreads();
    if (t == 0) out[b] = red[0] + red[1] + red[2] + red[3] + bm3[0];
}

// ---------------- launch ----------------

extern "C" void kernel_launch(void* const* d_in, const int* in_sizes, int n_in,
                              void* d_out, int out_size, void* d_ws, size_t ws_size,
                              hipStream_t stream) {
    const float* node_feats = (const float*)d_in[0];
    const int* node_mask = (const int*)d_in[1];
    const int* text_mask = (const int*)d_in[2];
    const int* image_mask = (const int*)d_in[3];
    const int* gidx = (const int*)d_in[4];
    const int* edge_index = (const int*)d_in[5];
    const int* edge_type = (const int*)d_in[6];
    const float* edge_weight = (const float*)d_in[7];
    const float* W_in = (const float*)d_in[8];
    const float* b_in = (const float*)d_in[9];
    const float* Wqkv = (const float*)d_in[10];
    const float* bqkv = (const float*)d_in[11];
    const float* Wo = (const float*)d_in[12];
    const float* bo = (const float*)d_in[13];
    const float* ln1_g = (const float*)d_in[14];
    const float* ln1_b = (const float*)d_in[15];
    const float* ln2_g = (const float*)d_in[16];
    const float* ln2_b = (const float*)d_in[17];
    const float* Wff1 = (const float*)d_in[18];
    const float* bff1 = (const float*)d_in[19];
    const float* Wff2 = (const float*)d_in[20];
    const float* bff2 = (const float*)d_in[21];
    const float* et_emb = (const float*)d_in[22];
    const float* Wm1 = (const float*)d_in[23];
    const float* bm1 = (const float*)d_in[24];
    const float* Wm2 = (const float*)d_in[25];
    const float* bm2 = (const float*)d_in[26];
    const float* Wm3 = (const float*)d_in[27];
    const float* bm3 = (const float*)d_in[28];

    const int M = Bb * Nn; // 8192
    char* ws = (char*)d_ws;
    size_t off = 0;
    auto alloc = [&](size_t bytes) {
        void* p = ws + off;
        off += (bytes + 255) & ~(size_t)255;
        return p;
    };
    float* x = (float*)alloc((size_t)M * Dd * 4);        // 8 MB
    float* qkvb = (float*)alloc((size_t)M * FF * 4);     // 32 MB union (qkv 24MB / ff 32MB)
    float* ffb = qkvb;
    float* attnout = (float*)alloc((size_t)M * Dd * 4);  // 8 MB
    float* projb = (float*)alloc((size_t)M * Dd * 4);    // 8 MB
    int* counts = (int*)alloc(8192 * 4);
    int* offsets = (int*)alloc(8193 * 4);
    int* cursor = (int*)alloc(8192 * 4);
    int* elist = (int*)alloc((size_t)Bb * Ee * 4);
    float* pools = (float*)alloc((size_t)Bb * 514 * 4);
    float* comb = (float*)alloc((size_t)Bb * 776 * 4);
    float* h1 = (float*)alloc((size_t)Bb * 512 * 4);
    (void)ws_size;

    zero_kernel<<<32, 256, 0, stream>>>(counts, 8192);
    zero_kernel<<<(Bb * 514 + 255) / 256, 256, 0, stream>>>((int*)pools, Bb * 514);
    count_kernel<<<256, 256, 0, stream>>>(edge_index, counts);
    scan_kernel<<<1, 1024, 0, stream>>>(counts, offsets, cursor);
    scatter_kernel<<<256, 256, 0, stream>>>(edge_index, cursor, elist);

    gemm128x64<<<dim3(Dd / 64, M / 128), 256, 0, stream>>>(node_feats, W_in, b_in, x, M, INDIM, Dd, 0);

    for (int l = 0; l < Ll; l++) {
        gemm128<<<dim3(768 / 128, M / 128), 256, 0, stream>>>(
            x, Wqkv + (size_t)l * Dd * 768, bqkv + l * 768, qkvb, M, Dd, 768, 0);
        attn_kernel<<<Bb * Hh * 2, 512, 0, stream>>>(
            qkvb, node_mask, offsets, elist, edge_index, edge_type, edge_weight, et_emb, attnout);
        gemm128x64<<<dim3(Dd / 64, M / 128), 256, 0, stream>>>(
            attnout, Wo + (size_t)l * Dd * Dd, bo + l * Dd, projb, M, Dd, Dd, 0);
        ln_kernel<<<M, 256, 0, stream>>>(x, projb, ln1_g + l * Dd, ln1_b + l * Dd);
        gemm128<<<dim3(FF / 128, M / 128), 256, 0, stream>>>(
            x, Wff1 + (size_t)l * Dd * FF, bff1 + l * FF, ffb, M, Dd, FF, 1);
        gemm128x64<<<dim3(Dd / 64, M / 128), 256, 0, stream>>>(
            ffb, Wff2 + (size_t)l * FF * Dd, bff2 + l * Dd, projb, M, FF, Dd, 0);
        ln_kernel<<<M, 256, 0, stream>>>(x, projb, ln2_g + l * Dd, ln2_b + l * Dd);
    }

    pool_kernel<<<dim3(16, Bb), 256, 0, stream>>>(x, text_mask, image_mask, pools);
    comb_kernel<<<Bb, 256, 0, stream>>>(x, pools, gidx, comb);
    h1_kernel<<<dim3(4, Bb), 256, 0, stream>>>(comb, Wm1, bm1, h1);
    head_fin<<<Bb, 256, 0, stream>>>(h1, Wm2, bm2, Wm3, bm3, (float*)d_out);
}

// Round 8
// 943.485 us; speedup vs baseline: 1.5363x; 1.5363x over previous
//
#include <hip/hip_runtime.h>
#include <hip/hip_bf16.h>
#include <math.h>

#define Bb 16
#define Nn 512
#define Dd 256
#define Hh 8
#define HD 32
#define Ll 3
#define INDIM 768
#define Ee 4096
#define FF 1024
#define KTP 516  // attn KT row pitch
#define KP 40    // gemm LDS k-pitch in shorts (32 + 8 pad)

typedef unsigned short u16;
typedef __bf16 bf16x8 __attribute__((ext_vector_type(8)));
typedef float f32x4 __attribute__((ext_vector_type(4)));
typedef u16 us8 __attribute__((ext_vector_type(8)));
typedef u16 us4 __attribute__((ext_vector_type(4)));

__device__ __forceinline__ float gelu_exact(float x) {
    return 0.5f * x * (1.0f + erff(x * 0.70710678118654752f));
}

__device__ __forceinline__ u16 f2bf(float x) {
    unsigned int u = __float_as_uint(x);
    return (u16)((u + 0x7FFFu + ((u >> 16) & 1u)) >> 16);
}
__device__ __forceinline__ float bf2f(u16 h) {
    return __uint_as_float(((unsigned int)h) << 16);
}

// ---------------- edge bucketing ----------------

__global__ __launch_bounds__(256) void zero_kernel(int* __restrict__ p, int n) {
    int gid = blockIdx.x * 256 + threadIdx.x;
    if (gid < n) p[gid] = 0;
}

__global__ __launch_bounds__(256) void count_kernel(const int* __restrict__ edge_index,
                                                    int* __restrict__ counts) {
    int gid = blockIdx.x * 256 + threadIdx.x; // B*E = 65536
    int b = gid >> 12;
    int e = gid & (Ee - 1);
    int src = edge_index[b * 2 * Ee + e];
    atomicAdd(&counts[b * Nn + src], 1);
}

__global__ __launch_bounds__(1024) void scan_kernel(const int* __restrict__ counts,
                                                    int* __restrict__ offsets,
                                                    int* __restrict__ cursor) {
    __shared__ int ssum[1024];
    int t = threadIdx.x;
    int local[8];
    int s = 0;
#pragma unroll
    for (int i = 0; i < 8; i++) { local[i] = counts[t * 8 + i]; s += local[i]; }
    ssum[t] = s;
    __syncthreads();
    for (int off = 1; off < 1024; off *= 2) {
        __syncthreads();
        int v = (t >= off) ? ssum[t - off] : 0;
        __syncthreads();
        ssum[t] += v;
    }
    __syncthreads();
    int base = (t > 0) ? ssum[t - 1] : 0;
#pragma unroll
    for (int i = 0; i < 8; i++) {
        offsets[t * 8 + i] = base;
        cursor[t * 8 + i] = base;
        base += local[i];
    }
    if (t == 1023) offsets[8192] = base;
}

__global__ __launch_bounds__(256) void scatter_kernel(const int* __restrict__ edge_index,
                                                      int* __restrict__ cursor,
                                                      int* __restrict__ elist) {
    int gid = blockIdx.x * 256 + threadIdx.x;
    int b = gid >> 12;
    int e = gid & (Ee - 1);
    int src = edge_index[b * 2 * Ee + e];
    int pos = atomicAdd(&cursor[b * Nn + src], 1);
    elist[pos] = gid;
}

// ---------------- weight split+transpose: W[K][N] fp32 -> Wh,Wl [N][K] bf16 ----------------

__global__ __launch_bounds__(256) void wsplit(const float* __restrict__ W,
                                              u16* __restrict__ Wh,
                                              u16* __restrict__ Wl,
                                              int K, int N) {
    size_t moff = (size_t)blockIdx.z * K * N;
    const float* Ws = W + moff;
    u16* Whs = Wh + moff;
    u16* Wls = Wl + moff;
    int n = blockIdx.x * 256 + threadIdx.x;
    int k0 = blockIdx.y * 8;
    float w[8];
#pragma unroll
    for (int i = 0; i < 8; i++) w[i] = Ws[(size_t)(k0 + i) * N + n];
    u16 h[8], l[8];
#pragma unroll
    for (int i = 0; i < 8; i++) {
        h[i] = f2bf(w[i]);
        l[i] = f2bf(w[i] - bf2f(h[i]));
    }
    us8 hv = {h[0], h[1], h[2], h[3], h[4], h[5], h[6], h[7]};
    us8 lv = {l[0], l[1], l[2], l[3], l[4], l[5], l[6], l[7]};
    *(us8*)&Whs[(size_t)n * K + k0] = hv;
    *(us8*)&Wls[(size_t)n * K + k0] = lv;
}

// ---------------- MFMA GEMM (bf16x3 split): C = A(MxK) @ W(KxN) + bias, opt GELU ----------
// Tile 64(M) x 128(N), BK=32, 256 threads = 4 waves in 2x2; wave tile 32x64 = 2x4 MFMA tiles.
// B pre-split/transposed to [N][K] bf16 hi/lo; A split on the fly.
// Fragment layouts (m89/m120-verified): A[m=lane&15][k=quad*8+j]; B[k=quad*8+j][n=lane&15];
// D[row=quad*4+r][col=lane&15].

__global__ __launch_bounds__(256) void gemm_mfma(const float* __restrict__ A,
                                                 const u16* __restrict__ Bh,
                                                 const u16* __restrict__ Bl,
                                                 const float* __restrict__ bias,
                                                 float* __restrict__ C,
                                                 int M, int K, int N, int act) {
    __shared__ u16 sAh[64 * KP];
    __shared__ u16 sAl[64 * KP];
    __shared__ u16 sBh[128 * KP];
    __shared__ u16 sBl[128 * KP];

    int t = threadIdx.x;
    int w = t >> 6, L = t & 63;
    int wr = w >> 1, wc = w & 1;
    int lane15 = L & 15, quad = L >> 4;
    int row0 = blockIdx.y * 64, col0 = blockIdx.x * 128;

    f32x4 acc[2][4];
#pragma unroll
    for (int mi = 0; mi < 2; mi++)
#pragma unroll
        for (int ni = 0; ni < 4; ni++) acc[mi][ni] = {0.f, 0.f, 0.f, 0.f};

    // staging index precompute
    int ar0 = t >> 3, akq0 = (t & 7) * 4;             // A unit 0 (idx = t)
    int ar1 = (t + 256) >> 3, akq1 = akq0;            // A unit 1 (idx = t+256)
    int bn0 = t >> 2, bk0 = (t & 3) * 8;              // B unit 0 (u = t)
    int bn1 = (t + 256) >> 2, bk1 = bk0;              // B unit 1 (u = t+256)

    const float* Ap0 = &A[(size_t)(row0 + ar0) * K + akq0];
    const float* Ap1 = &A[(size_t)(row0 + ar1) * K + akq1];
    const u16* Bhp0 = &Bh[(size_t)(col0 + bn0) * K + bk0];
    const u16* Bhp1 = &Bh[(size_t)(col0 + bn1) * K + bk1];
    const u16* Blp0 = &Bl[(size_t)(col0 + bn0) * K + bk0];
    const u16* Blp1 = &Bl[(size_t)(col0 + bn1) * K + bk1];

    // prologue loads (tile 0)
    float4 av0 = *(const float4*)&Ap0[0];
    float4 av1 = *(const float4*)&Ap1[0];
    us8 bhv0 = *(const us8*)&Bhp0[0];
    us8 bhv1 = *(const us8*)&Bhp1[0];
    us8 blv0 = *(const us8*)&Blp0[0];
    us8 blv1 = *(const us8*)&Blp1[0];

    for (int k0 = 0; k0 < K; k0 += 32) {
        __syncthreads();  // previous tile's frag reads complete
        // A: convert + write hi/lo (b64 each)
        {
            float a[4] = {av0.x, av0.y, av0.z, av0.w};
            u16 h[4], l[4];
#pragma unroll
            for (int i = 0; i < 4; i++) { h[i] = f2bf(a[i]); l[i] = f2bf(a[i] - bf2f(h[i])); }
            us4 hv = {h[0], h[1], h[2], h[3]};
            us4 lv = {l[0], l[1], l[2], l[3]};
            *(us4*)&sAh[ar0 * KP + akq0] = hv;
            *(us4*)&sAl[ar0 * KP + akq0] = lv;
        }
        {
            float a[4] = {av1.x, av1.y, av1.z, av1.w};
            u16 h[4], l[4];
#pragma unroll
            for (int i = 0; i < 4; i++) { h[i] = f2bf(a[i]); l[i] = f2bf(a[i] - bf2f(h[i])); }
            us4 hv = {h[0], h[1], h[2], h[3]};
            us4 lv = {l[0], l[1], l[2], l[3]};
            *(us4*)&sAh[ar1 * KP + akq1] = hv;
            *(us4*)&sAl[ar1 * KP + akq1] = lv;
        }
        // B: straight b128 writes
        *(us8*)&sBh[bn0 * KP + bk0] = bhv0;
        *(us8*)&sBh[bn1 * KP + bk1] = bhv1;
        *(us8*)&sBl[bn0 * KP + bk0] = blv0;
        *(us8*)&sBl[bn1 * KP + bk1] = blv1;
        __syncthreads();

        // prefetch next tile
        if (k0 + 32 < K) {
            av0 = *(const float4*)&Ap0[k0 + 32];
            av1 = *(const float4*)&Ap1[k0 + 32];
            bhv0 = *(const us8*)&Bhp0[k0 + 32];
            bhv1 = *(const us8*)&Bhp1[k0 + 32];
            blv0 = *(const us8*)&Blp0[k0 + 32];
            blv1 = *(const us8*)&Blp1[k0 + 32];
        }

        // fragments
        us8 ahr[2], alr[2], bhr[4], blr[4];
#pragma unroll
        for (int mi = 0; mi < 2; mi++) {
            int ro = (wr * 32 + mi * 16 + lane15) * KP + quad * 8;
            ahr[mi] = *(const us8*)&sAh[ro];
            alr[mi] = *(const us8*)&sAl[ro];
        }
#pragma unroll
        for (int ni = 0; ni < 4; ni++) {
            int ro = (wc * 64 + ni * 16 + lane15) * KP + quad * 8;
            bhr[ni] = *(const us8*)&sBh[ro];
            blr[ni] = *(const us8*)&sBl[ro];
        }
#pragma unroll
        for (int mi = 0; mi < 2; mi++) {
            bf16x8 ah = *(const bf16x8*)&ahr[mi];
            bf16x8 al = *(const bf16x8*)&alr[mi];
#pragma unroll
            for (int ni = 0; ni < 4; ni++) {
                bf16x8 bh = *(const bf16x8*)&bhr[ni];
                bf16x8 bl = *(const bf16x8*)&blr[ni];
                acc[mi][ni] = __builtin_amdgcn_mfma_f32_16x16x32_bf16(ah, bh, acc[mi][ni], 0, 0, 0);
                acc[mi][ni] = __builtin_amdgcn_mfma_f32_16x16x32_bf16(ah, bl, acc[mi][ni], 0, 0, 0);
                acc[mi][ni] = __builtin_amdgcn_mfma_f32_16x16x32_bf16(al, bh, acc[mi][ni], 0, 0, 0);
            }
        }
    }

    // epilogue
#pragma unroll
    for (int mi = 0; mi < 2; mi++) {
#pragma unroll
        for (int ni = 0; ni < 4; ni++) {
            int col = col0 + wc * 64 + ni * 16 + lane15;
            float bcol = bias[col];
#pragma unroll
            for (int r = 0; r < 4; r++) {
                int row = row0 + wr * 32 + mi * 16 + quad * 4 + r;
                float u = acc[mi][ni][r] + bcol;
                if (act == 1) u = gelu_exact(u);
                C[(size_t)row * N + col] = u;
            }
        }
    }
}

// ---------------- attention (R5/v4, measured 148 us): one block per (b,h,half) ----------------

__global__ __launch_bounds__(512, 1) void attn_kernel(const float* __restrict__ qkv,
                                                      const int* __restrict__ node_mask,
                                                      const int* __restrict__ offsets,
                                                      const int* __restrict__ elist,
                                                      const int* __restrict__ edge_index,
                                                      const int* __restrict__ edge_type,
                                                      const float* __restrict__ edge_weight,
                                                      const float* __restrict__ et_emb,
                                                      float* __restrict__ outbuf) {
    int bid = blockIdx.x;          // b*16 + h*2 + half
    int half = bid & 1;
    int h = (bid >> 1) & 7;
    int b = bid >> 4;
    int t = threadIdx.x;
    int w = t >> 6;   // wave 0..7
    int L = t & 63;   // lane

    __shared__ __align__(16) float KT[HD][KTP];
    __shared__ __align__(16) float srow[8][4][Nn];

    for (int i = t; i < Nn * HD; i += 512) {
        int m = i >> 5, d = i & 31;
        KT[d][m] = qkv[(size_t)(b * Nn + m) * 768 + 256 + h * HD + d];
    }
    __syncthreads();

    const float scale = 0.17677669529663687f;
    int base = half * 256;
    int m4 = 4 * L;

    int4 nm0 = *(const int4*)&node_mask[b * Nn + m4];
    int4 nm1 = *(const int4*)&node_mask[b * Nn + 256 + m4];
    float mb[8];
    mb[0] = nm0.x ? 0.0f : -INFINITY;
    mb[1] = nm0.y ? 0.0f : -INFINITY;
    mb[2] = nm0.z ? 0.0f : -INFINITY;
    mb[3] = nm0.w ? 0.0f : -INFINITY;
    mb[4] = nm1.x ? 0.0f : -INFINITY;
    mb[5] = nm1.y ? 0.0f : -INFINITY;
    mb[6] = nm1.z ? 0.0f : -INFINITY;
    mb[7] = nm1.w ? 0.0f : -INFINITY;

    for (int g = 0; g < 8; g++) {
        int n0 = base + w * 32 + g * 4;

        float qr[4];
#pragma unroll
        for (int r = 0; r < 4; r++)
            qr[r] = qkv[(size_t)(b * Nn + n0 + r) * 768 + h * HD + (L & 31)] * scale;

        float acc[4][8];
#pragma unroll
        for (int r = 0; r < 4; r++)
#pragma unroll
            for (int j = 0; j < 8; j++) acc[r][j] = 0.0f;
#pragma unroll 4
        for (int d = 0; d < HD; d++) {
            float4 k0 = *(const float4*)&KT[d][m4];
            float4 k1 = *(const float4*)&KT[d][256 + m4];
            float kk[8] = {k0.x, k0.y, k0.z, k0.w, k1.x, k1.y, k1.z, k1.w};
            float q0 = __shfl(qr[0], d);
            float q1 = __shfl(qr[1], d);
            float q2 = __shfl(qr[2], d);
            float q3 = __shfl(qr[3], d);
#pragma unroll
            for (int j = 0; j < 8; j++) {
                acc[0][j] += q0 * kk[j];
                acc[1][j] += q1 * kk[j];
                acc[2][j] += q2 * kk[j];
                acc[3][j] += q3 * kk[j];
            }
        }

#pragma unroll
        for (int r = 0; r < 4; r++) {
            *(float4*)&srow[w][r][m4] = make_float4(acc[r][0], acc[r][1], acc[r][2], acc[r][3]);
            *(float4*)&srow[w][r][256 + m4] = make_float4(acc[r][4], acc[r][5], acc[r][6], acc[r][7]);
        }

        int beg = offsets[b * Nn + n0];
        int end = offsets[b * Nn + n0 + 4];
        for (int i = beg + L; i < end; i += 64) {
            int ge = elist[i];
            int e = ge & (Ee - 1);
            int src = edge_index[b * 2 * Ee + e];
            int dst = edge_index[b * 2 * Ee + Ee + e];
            int ty = edge_type[b * Ee + e];
            float wgt = edge_weight[b * Ee + e];
            float val = et_emb[ty * Hh + h] + (ty == 2 ? wgt : 0.0f);
            atomicAdd(&srow[w][src - n0][dst], val);
        }
        asm volatile("s_waitcnt lgkmcnt(0)" ::: "memory");

        float inv[4];
#pragma unroll
        for (int r = 0; r < 4; r++) {
            float4 s0 = *(const float4*)&srow[w][r][m4];
            float4 s1 = *(const float4*)&srow[w][r][256 + m4];
            float s[8] = {s0.x, s0.y, s0.z, s0.w, s1.x, s1.y, s1.z, s1.w};
#pragma unroll
            for (int j = 0; j < 8; j++) s[j] += mb[j];
            float mx = s[0];
#pragma unroll
            for (int j = 1; j < 8; j++) mx = fmaxf(mx, s[j]);
#pragma unroll
            for (int o = 1; o < 64; o <<= 1) mx = fmaxf(mx, __shfl_xor(mx, o));
            float sum = 0.0f;
#pragma unroll
            for (int j = 0; j < 8; j++) {
                s[j] = __expf(s[j] - mx);
                sum += s[j];
            }
#pragma unroll
            for (int o = 1; o < 64; o <<= 1) sum += __shfl_xor(sum, o);
            inv[r] = 1.0f / sum;
            *(float4*)&srow[w][r][m4] = make_float4(s[0], s[1], s[2], s[3]);
            *(float4*)&srow[w][r][256 + m4] = make_float4(s[4], s[5], s[6], s[7]);
        }
        asm volatile("s_waitcnt lgkmcnt(0)" ::: "memory");

        int d = L & 31, h2 = L >> 5;
        int mbase = h2 * 256;
        const float* vp = qkv + (size_t)(b * Nn + mbase) * 768 + 512 + h * HD + d;
        float o0 = 0.0f, o1 = 0.0f, o2 = 0.0f, o3 = 0.0f;
#pragma unroll 2
        for (int mc = 0; mc < 256; mc += 8) {
            float v[8];
#pragma unroll
            for (int u = 0; u < 8; u++) v[u] = vp[(size_t)(mc + u) * 768];
#pragma unroll
            for (int p = 0; p < 2; p++) {
                float4 s0 = *(const float4*)&srow[w][0][mbase + mc + p * 4];
                float4 s1 = *(const float4*)&srow[w][1][mbase + mc + p * 4];
                float4 s2 = *(const float4*)&srow[w][2][mbase + mc + p * 4];
                float4 s3 = *(const float4*)&srow[w][3][mbase + mc + p * 4];
                float* vb = &v[p * 4];
                o0 += s0.x * vb[0] + s0.y * vb[1] + s0.z * vb[2] + s0.w * vb[3];
                o1 += s1.x * vb[0] + s1.y * vb[1] + s1.z * vb[2] + s1.w * vb[3];
                o2 += s2.x * vb[0] + s2.y * vb[1] + s2.z * vb[2] + s2.w * vb[3];
                o3 += s3.x * vb[0] + s3.y * vb[1] + s3.z * vb[2] + s3.w * vb[3];
            }
        }
        o0 += __shfl_xor(o0, 32);
        o1 += __shfl_xor(o1, 32);
        o2 += __shfl_xor(o2, 32);
        o3 += __shfl_xor(o3, 32);
        if (h2 == 0) {
            outbuf[(size_t)(b * Nn + n0 + 0) * Dd + h * HD + d] = o0 * inv[0];
            outbuf[(size_t)(b * Nn + n0 + 1) * Dd + h * HD + d] = o1 * inv[1];
            outbuf[(size_t)(b * Nn + n0 + 2) * Dd + h * HD + d] = o2 * inv[2];
            outbuf[(size_t)(b * Nn + n0 + 3) * Dd + h * HD + d] = o3 * inv[3];
        }
    }
}

// ---------------- residual + LayerNorm ----------------

__global__ __launch_bounds__(256) void ln_kernel(float* __restrict__ x,
                                                 const float* __restrict__ res,
                                                 const float* __restrict__ g,
                                                 const float* __restrict__ bta) {
    int row = blockIdx.x;
    int t = threadIdx.x;
    __shared__ float red[4];
    __shared__ float stats[2];
    size_t idx = (size_t)row * Dd + t;
    float v = x[idx] + res[idx];
    float sm = v;
    for (int o = 32; o > 0; o >>= 1) sm += __shfl_down(sm, o);
    if ((t & 63) == 0) red[t >> 6] = sm;
    __syncthreads();
    if (t == 0) stats[0] = (red[0] + red[1] + red[2] + red[3]) * (1.0f / Dd);
    __syncthreads();
    float mu = stats[0];
    float dv = v - mu;
    float s2 = dv * dv;
    for (int o = 32; o > 0; o >>= 1) s2 += __shfl_down(s2, o);
    if ((t & 63) == 0) red[t >> 6] = s2;
    __syncthreads();
    if (t == 0) stats[1] = 1.0f / sqrtf((red[0] + red[1] + red[2] + red[3]) * (1.0f / Dd) + 1e-5f);
    __syncthreads();
    x[idx] = dv * stats[1] * g[t] + bta[t];
}

// ---------------- head ----------------

__global__ __launch_bounds__(256) void pool_kernel(const float* __restrict__ x,
                                                   const int* __restrict__ text_mask,
                                                   const int* __restrict__ image_mask,
                                                   float* __restrict__ pools) {
    int b = blockIdx.y;
    int n0 = blockIdx.x * 32;
    int t = threadIdx.x;
    float tp = 0.0f, ip = 0.0f, c1 = 0.0f, c2 = 0.0f;
    for (int n = n0; n < n0 + 32; n++) {
        float xv = x[(size_t)(b * Nn + n) * Dd + t];
        int tm = text_mask[b * Nn + n];
        int im = image_mask[b * Nn + n];
        tp += tm ? xv : 0.0f;
        ip += im ? xv : 0.0f;
        c1 += (float)tm;
        c2 += (float)im;
    }
    atomicAdd(&pools[b * 514 + t], tp);
    atomicAdd(&pools[b * 514 + 256 + t], ip);
    if (t == 0) {
        atomicAdd(&pools[b * 514 + 512], c1);
        atomicAdd(&pools[b * 514 + 513], c2);
    }
}

__global__ __launch_bounds__(256) void comb_kernel(const float* __restrict__ x,
                                                   const float* __restrict__ pools,
                                                   const int* __restrict__ gidx,
                                                   float* __restrict__ comb) {
    int b = blockIdx.x;
    int t = threadIdx.x;
    __shared__ float redd[12];
    float tc = fmaxf(pools[b * 514 + 512], 1.0f);
    float ic = fmaxf(pools[b * 514 + 513], 1.0f);
    float tp = pools[b * 514 + t] / tc;
    float ip = pools[b * 514 + 256 + t] / ic;
    int gi = gidx[b];
    comb[b * 776 + t] = x[(size_t)(b * Nn + gi) * Dd + t];
    comb[b * 776 + 256 + t] = tp;
    comb[b * 776 + 512 + t] = ip;
    float dotv = tp * ip, n1v = tp * tp, n2v = ip * ip;
    for (int o = 32; o > 0; o >>= 1) {
        dotv += __shfl_down(dotv, o);
        n1v += __shfl_down(n1v, o);
        n2v += __shfl_down(n2v, o);
    }
    if ((t & 63) == 0) { redd[t >> 6] = dotv; redd[4 + (t >> 6)] = n1v; redd[8 + (t >> 6)] = n2v; }
    __syncthreads();
    if (t == 0) {
        float dd = redd[0] + redd[1] + redd[2] + redd[3];
        float a1 = fmaxf(sqrtf(redd[4] + redd[5] + redd[6] + redd[7]), 1e-6f);
        float a2 = fmaxf(sqrtf(redd[8] + redd[9] + redd[10] + redd[11]), 1e-6f);
        comb[b * 776 + 768] = 1.0f - dd / (a1 * a2);
    }
}

__global__ __launch_bounds__(256) void h1_kernel(const float* __restrict__ comb,
                                                 const float* __restrict__ Wm1,
                                                 const float* __restrict__ bm1,
                                                 float* __restrict__ h1) {
    int b = blockIdx.y;
    int jc = blockIdx.x;
    int t = threadIdx.x;
    __shared__ float scomb[776];
    __shared__ float partial[2][128];
    for (int i = t; i < 769; i += 256) scomb[i] = comb[b * 776 + i];
    __syncthreads();
    int j = jc * 128 + (t & 127);
    int kh = t >> 7;
    int kbeg = kh ? 384 : 0;
    int kend = kh ? 769 : 384;
    float acc = 0.0f;
#pragma unroll 8
    for (int k = kbeg; k < kend; k++) acc += scomb[k] * Wm1[k * 512 + j];
    partial[kh][t & 127] = acc;
    __syncthreads();
    if (t < 128) {
        float v = partial[0][t] + partial[1][t] + bm1[jc * 128 + t];
        h1[b * 512 + jc * 128 + t] = gelu_exact(v);
    }
}

__global__ __launch_bounds__(256) void head_fin(const float* __restrict__ h1,
                                                const float* __restrict__ Wm2,
                                                const float* __restrict__ bm2,
                                                const float* __restrict__ Wm3,
                                                const float* __restrict__ bm3,
                                                float* __restrict__ out) {
    int b = blockIdx.x;
    int t = threadIdx.x;
    __shared__ float h1s[512];
    __shared__ float red[4];
    for (int i = t; i < 512; i += 256) h1s[i] = h1[b * 512 + i];
    __syncthreads();
    float acc = bm2[t];
#pragma unroll 8
    for (int k = 0; k < 512; k++) acc += h1s[k] * Wm2[k * 256 + t];
    float h2 = gelu_exact(acc);
    float lv = h2 * Wm3[t];
    for (int o = 32; o > 0; o >>= 1) lv += __shfl_down(lv, o);
    if ((t & 63) == 0) red[t >> 6] = lv;
    __syncthreads();
    if (t == 0) out[b] = red[0] + red[1] + red[2] + red[3] + bm3[0];
}

// ---------------- launch ----------------

// split-weight element offsets
#define OFF_IN  0
#define OFF_QKV 196608
#define OFF_O   786432
#define OFF_F1  983040
#define OFF_F2  1769472
#define W_TOTAL 2555904

extern "C" void kernel_launch(void* const* d_in, const int* in_sizes, int n_in,
                              void* d_out, int out_size, void* d_ws, size_t ws_size,
                              hipStream_t stream) {
    const float* node_feats = (const float*)d_in[0];
    const int* node_mask = (const int*)d_in[1];
    const int* text_mask = (const int*)d_in[2];
    const int* image_mask = (const int*)d_in[3];
    const int* gidx = (const int*)d_in[4];
    const int* edge_index = (const int*)d_in[5];
    const int* edge_type = (const int*)d_in[6];
    const float* edge_weight = (const float*)d_in[7];
    const float* W_in = (const float*)d_in[8];
    const float* b_in = (const float*)d_in[9];
    const float* Wqkv = (const float*)d_in[10];
    const float* bqkv = (const float*)d_in[11];
    const float* Wo = (const float*)d_in[12];
    const float* bo = (const float*)d_in[13];
    const float* ln1_g = (const float*)d_in[14];
    const float* ln1_b = (const float*)d_in[15];
    const float* ln2_g = (const float*)d_in[16];
    const float* ln2_b = (const float*)d_in[17];
    const float* Wff1 = (const float*)d_in[18];
    const float* bff1 = (const float*)d_in[19];
    const float* Wff2 = (const float*)d_in[20];
    const float* bff2 = (const float*)d_in[21];
    const float* et_emb = (const float*)d_in[22];
    const float* Wm1 = (const float*)d_in[23];
    const float* bm1 = (const float*)d_in[24];
    const float* Wm2 = (const float*)d_in[25];
    const float* bm2 = (const float*)d_in[26];
    const float* Wm3 = (const float*)d_in[27];
    const float* bm3 = (const float*)d_in[28];

    const int M = Bb * Nn; // 8192
    char* ws = (char*)d_ws;
    size_t off = 0;
    auto alloc = [&](size_t bytes) {
        void* p = ws + off;
        off += (bytes + 255) & ~(size_t)255;
        return p;
    };
    float* x = (float*)alloc((size_t)M * Dd * 4);        // 8 MB
    float* qkvb = (float*)alloc((size_t)M * FF * 4);     // 32 MB union (qkv 24MB / ff 32MB)
    float* ffb = qkvb;
    float* attnout = (float*)alloc((size_t)M * Dd * 4);  // 8 MB
    float* projb = (float*)alloc((size_t)M * Dd * 4);    // 8 MB
    int* counts = (int*)alloc(8192 * 4);
    int* offsets = (int*)alloc(8193 * 4);
    int* cursor = (int*)alloc(8192 * 4);
    int* elist = (int*)alloc((size_t)Bb * Ee * 4);
    float* pools = (float*)alloc((size_t)Bb * 514 * 4);
    float* comb = (float*)alloc((size_t)Bb * 776 * 4);
    float* h1 = (float*)alloc((size_t)Bb * 512 * 4);
    u16* wh = (u16*)alloc((size_t)W_TOTAL * 2);          // ~5.1 MB
    u16* wl = (u16*)alloc((size_t)W_TOTAL * 2);          // ~5.1 MB
    (void)ws_size;

    // edge buckets + pool zero
    zero_kernel<<<32, 256, 0, stream>>>(counts, 8192);
    zero_kernel<<<(Bb * 514 + 255) / 256, 256, 0, stream>>>((int*)pools, Bb * 514);
    count_kernel<<<256, 256, 0, stream>>>(edge_index, counts);
    scan_kernel<<<1, 1024, 0, stream>>>(counts, offsets, cursor);
    scatter_kernel<<<256, 256, 0, stream>>>(edge_index, cursor, elist);

    // weight split+transpose (bf16 hi/lo, [N][K])
    wsplit<<<dim3(1, 96, 1), 256, 0, stream>>>(W_in, wh + OFF_IN, wl + OFF_IN, 768, 256);
    wsplit<<<dim3(3, 32, 3), 256, 0, stream>>>(Wqkv, wh + OFF_QKV, wl + OFF_QKV, 256, 768);
    wsplit<<<dim3(1, 32, 3), 256, 0, stream>>>(Wo, wh + OFF_O, wl + OFF_O, 256, 256);
    wsplit<<<dim3(4, 32, 3), 256, 0, stream>>>(Wff1, wh + OFF_F1, wl + OFF_F1, 256, 1024);
    wsplit<<<dim3(1, 128, 3), 256, 0, stream>>>(Wff2, wh + OFF_F2, wl + OFF_F2, 1024, 256);

    // input projection
    gemm_mfma<<<dim3(Dd / 128, M / 64), 256, 0, stream>>>(
        node_feats, wh + OFF_IN, wl + OFF_IN, b_in, x, M, INDIM, Dd, 0);

    for (int l = 0; l < Ll; l++) {
        gemm_mfma<<<dim3(768 / 128, M / 64), 256, 0, stream>>>(
            x, wh + OFF_QKV + (size_t)l * 196608, wl + OFF_QKV + (size_t)l * 196608,
            bqkv + l * 768, qkvb, M, Dd, 768, 0);
        attn_kernel<<<Bb * Hh * 2, 512, 0, stream>>>(
            qkvb, node_mask, offsets, elist, edge_index, edge_type, edge_weight, et_emb, attnout);
        gemm_mfma<<<dim3(Dd / 128, M / 64), 256, 0, stream>>>(
            attnout, wh + OFF_O + (size_t)l * 65536, wl + OFF_O + (size_t)l * 65536,
            bo + l * Dd, projb, M, Dd, Dd, 0);
        ln_kernel<<<M, 256, 0, stream>>>(x, projb, ln1_g + l * Dd, ln1_b + l * Dd);
        gemm_mfma<<<dim3(FF / 128, M / 64), 256, 0, stream>>>(
            x, wh + OFF_F1 + (size_t)l * 262144, wl + OFF_F1 + (size_t)l * 262144,
            bff1 + l * FF, ffb, M, Dd, FF, 1);
        gemm_mfma<<<dim3(Dd / 128, M / 64), 256, 0, stream>>>(
            ffb, wh + OFF_F2 + (size_t)l * 262144, wl + OFF_F2 + (size_t)l * 262144,
            bff2 + l * Dd, projb, M, FF, Dd, 0);
        ln_kernel<<<M, 256, 0, stream>>>(x, projb, ln2_g + l * Dd, ln2_b + l * Dd);
    }

    pool_kernel<<<dim3(16, Bb), 256, 0, stream>>>(x, text_mask, image_mask, pools);
    comb_kernel<<<Bb, 256, 0, stream>>>(x, pools, gidx, comb);
    h1_kernel<<<dim3(4, Bb), 256, 0, stream>>>(comb, Wm1, bm1, h1);
    head_fin<<<Bb, 256, 0, stream>>>(h1, Wm2, bm2, Wm3, bm3, (float*)d_out);
}

// Round 9
// 706.527 us; speedup vs baseline: 2.0515x; 1.3354x over previous
//
#include <hip/hip_runtime.h>
#include <hip/hip_bf16.h>
#include <math.h>

#define Bb 16
#define Nn 512
#define Dd 256
#define Hh 8
#define HD 32
#define Ll 3
#define INDIM 768
#define Ee 4096
#define FF 1024
#define KP 40    // gemm LDS k-pitch in shorts (32 + 8 pad)

typedef unsigned short u16;
typedef __bf16 bf16x8 __attribute__((ext_vector_type(8)));
typedef float f32x4 __attribute__((ext_vector_type(4)));
typedef u16 us8 __attribute__((ext_vector_type(8)));
typedef u16 us4 __attribute__((ext_vector_type(4)));

__device__ __forceinline__ float gelu_exact(float x) {
    return 0.5f * x * (1.0f + erff(x * 0.70710678118654752f));
}

__device__ __forceinline__ u16 f2bf(float x) {
    unsigned int u = __float_as_uint(x);
    return (u16)((u + 0x7FFFu + ((u >> 16) & 1u)) >> 16);
}
__device__ __forceinline__ float bf2f(u16 h) {
    return __uint_as_float(((unsigned int)h) << 16);
}

// ---------------- edge bucketing ----------------

__global__ __launch_bounds__(256) void zero_kernel(int* __restrict__ p, int n) {
    int gid = blockIdx.x * 256 + threadIdx.x;
    if (gid < n) p[gid] = 0;
}

__global__ __launch_bounds__(256) void count_kernel(const int* __restrict__ edge_index,
                                                    int* __restrict__ counts) {
    int gid = blockIdx.x * 256 + threadIdx.x; // B*E = 65536
    int b = gid >> 12;
    int e = gid & (Ee - 1);
    int src = edge_index[b * 2 * Ee + e];
    atomicAdd(&counts[b * Nn + src], 1);
}

__global__ __launch_bounds__(1024) void scan_kernel(const int* __restrict__ counts,
                                                    int* __restrict__ offsets,
                                                    int* __restrict__ cursor) {
    __shared__ int ssum[1024];
    int t = threadIdx.x;
    int local[8];
    int s = 0;
#pragma unroll
    for (int i = 0; i < 8; i++) { local[i] = counts[t * 8 + i]; s += local[i]; }
    ssum[t] = s;
    __syncthreads();
    for (int off = 1; off < 1024; off *= 2) {
        __syncthreads();
        int v = (t >= off) ? ssum[t - off] : 0;
        __syncthreads();
        ssum[t] += v;
    }
    __syncthreads();
    int base = (t > 0) ? ssum[t - 1] : 0;
#pragma unroll
    for (int i = 0; i < 8; i++) {
        offsets[t * 8 + i] = base;
        cursor[t * 8 + i] = base;
        base += local[i];
    }
    if (t == 1023) offsets[8192] = base;
}

__global__ __launch_bounds__(256) void scatter_kernel(const int* __restrict__ edge_index,
                                                      int* __restrict__ cursor,
                                                      int* __restrict__ elist) {
    int gid = blockIdx.x * 256 + threadIdx.x;
    int b = gid >> 12;
    int e = gid & (Ee - 1);
    int src = edge_index[b * 2 * Ee + e];
    int pos = atomicAdd(&cursor[b * Nn + src], 1);
    elist[pos] = gid;
}

// ---------------- weight split+transpose: W[K][N] fp32 -> Wh,Wl [N][K] bf16 ----------------

__global__ __launch_bounds__(256) void wsplit(const float* __restrict__ W,
                                              u16* __restrict__ Wh,
                                              u16* __restrict__ Wl,
                                              int K, int N) {
    size_t moff = (size_t)blockIdx.z * K * N;
    const float* Ws = W + moff;
    u16* Whs = Wh + moff;
    u16* Wls = Wl + moff;
    int n = blockIdx.x * 256 + threadIdx.x;
    int k0 = blockIdx.y * 8;
    float w[8];
#pragma unroll
    for (int i = 0; i < 8; i++) w[i] = Ws[(size_t)(k0 + i) * N + n];
    u16 h[8], l[8];
#pragma unroll
    for (int i = 0; i < 8; i++) {
        h[i] = f2bf(w[i]);
        l[i] = f2bf(w[i] - bf2f(h[i]));
    }
    us8 hv = {h[0], h[1], h[2], h[3], h[4], h[5], h[6], h[7]};
    us8 lv = {l[0], l[1], l[2], l[3], l[4], l[5], l[6], l[7]};
    *(us8*)&Whs[(size_t)n * K + k0] = hv;
    *(us8*)&Wls[(size_t)n * K + k0] = lv;
}

// ---------------- MFMA GEMM (bf16x3 split) ----------------

__global__ __launch_bounds__(256) void gemm_mfma(const float* __restrict__ A,
                                                 const u16* __restrict__ Bh,
                                                 const u16* __restrict__ Bl,
                                                 const float* __restrict__ bias,
                                                 float* __restrict__ C,
                                                 int M, int K, int N, int act) {
    __shared__ u16 sAh[64 * KP];
    __shared__ u16 sAl[64 * KP];
    __shared__ u16 sBh[128 * KP];
    __shared__ u16 sBl[128 * KP];

    int t = threadIdx.x;
    int w = t >> 6, L = t & 63;
    int wr = w >> 1, wc = w & 1;
    int lane15 = L & 15, quad = L >> 4;
    int row0 = blockIdx.y * 64, col0 = blockIdx.x * 128;

    f32x4 acc[2][4];
#pragma unroll
    for (int mi = 0; mi < 2; mi++)
#pragma unroll
        for (int ni = 0; ni < 4; ni++) acc[mi][ni] = {0.f, 0.f, 0.f, 0.f};

    int ar0 = t >> 3, akq0 = (t & 7) * 4;
    int ar1 = (t + 256) >> 3, akq1 = akq0;
    int bn0 = t >> 2, bk0 = (t & 3) * 8;
    int bn1 = (t + 256) >> 2, bk1 = bk0;

    const float* Ap0 = &A[(size_t)(row0 + ar0) * K + akq0];
    const float* Ap1 = &A[(size_t)(row0 + ar1) * K + akq1];
    const u16* Bhp0 = &Bh[(size_t)(col0 + bn0) * K + bk0];
    const u16* Bhp1 = &Bh[(size_t)(col0 + bn1) * K + bk1];
    const u16* Blp0 = &Bl[(size_t)(col0 + bn0) * K + bk0];
    const u16* Blp1 = &Bl[(size_t)(col0 + bn1) * K + bk1];

    float4 av0 = *(const float4*)&Ap0[0];
    float4 av1 = *(const float4*)&Ap1[0];
    us8 bhv0 = *(const us8*)&Bhp0[0];
    us8 bhv1 = *(const us8*)&Bhp1[0];
    us8 blv0 = *(const us8*)&Blp0[0];
    us8 blv1 = *(const us8*)&Blp1[0];

    for (int k0 = 0; k0 < K; k0 += 32) {
        __syncthreads();
        {
            float a[4] = {av0.x, av0.y, av0.z, av0.w};
            u16 h[4], l[4];
#pragma unroll
            for (int i = 0; i < 4; i++) { h[i] = f2bf(a[i]); l[i] = f2bf(a[i] - bf2f(h[i])); }
            us4 hv = {h[0], h[1], h[2], h[3]};
            us4 lv = {l[0], l[1], l[2], l[3]};
            *(us4*)&sAh[ar0 * KP + akq0] = hv;
            *(us4*)&sAl[ar0 * KP + akq0] = lv;
        }
        {
            float a[4] = {av1.x, av1.y, av1.z, av1.w};
            u16 h[4], l[4];
#pragma unroll
            for (int i = 0; i < 4; i++) { h[i] = f2bf(a[i]); l[i] = f2bf(a[i] - bf2f(h[i])); }
            us4 hv = {h[0], h[1], h[2], h[3]};
            us4 lv = {l[0], l[1], l[2], l[3]};
            *(us4*)&sAh[ar1 * KP + akq1] = hv;
            *(us4*)&sAl[ar1 * KP + akq1] = lv;
        }
        *(us8*)&sBh[bn0 * KP + bk0] = bhv0;
        *(us8*)&sBh[bn1 * KP + bk1] = bhv1;
        *(us8*)&sBl[bn0 * KP + bk0] = blv0;
        *(us8*)&sBl[bn1 * KP + bk1] = blv1;
        __syncthreads();

        if (k0 + 32 < K) {
            av0 = *(const float4*)&Ap0[k0 + 32];
            av1 = *(const float4*)&Ap1[k0 + 32];
            bhv0 = *(const us8*)&Bhp0[k0 + 32];
            bhv1 = *(const us8*)&Bhp1[k0 + 32];
            blv0 = *(const us8*)&Blp0[k0 + 32];
            blv1 = *(const us8*)&Blp1[k0 + 32];
        }

        us8 ahr[2], alr[2], bhr[4], blr[4];
#pragma unroll
        for (int mi = 0; mi < 2; mi++) {
            int ro = (wr * 32 + mi * 16 + lane15) * KP + quad * 8;
            ahr[mi] = *(const us8*)&sAh[ro];
            alr[mi] = *(const us8*)&sAl[ro];
        }
#pragma unroll
        for (int ni = 0; ni < 4; ni++) {
            int ro = (wc * 64 + ni * 16 + lane15) * KP + quad * 8;
            bhr[ni] = *(const us8*)&sBh[ro];
            blr[ni] = *(const us8*)&sBl[ro];
        }
#pragma unroll
        for (int mi = 0; mi < 2; mi++) {
            bf16x8 ah = *(const bf16x8*)&ahr[mi];
            bf16x8 al = *(const bf16x8*)&alr[mi];
#pragma unroll
            for (int ni = 0; ni < 4; ni++) {
                bf16x8 bh = *(const bf16x8*)&bhr[ni];
                bf16x8 bl = *(const bf16x8*)&blr[ni];
                acc[mi][ni] = __builtin_amdgcn_mfma_f32_16x16x32_bf16(ah, bh, acc[mi][ni], 0, 0, 0);
                acc[mi][ni] = __builtin_amdgcn_mfma_f32_16x16x32_bf16(ah, bl, acc[mi][ni], 0, 0, 0);
                acc[mi][ni] = __builtin_amdgcn_mfma_f32_16x16x32_bf16(al, bh, acc[mi][ni], 0, 0, 0);
            }
        }
    }

#pragma unroll
    for (int mi = 0; mi < 2; mi++) {
#pragma unroll
        for (int ni = 0; ni < 4; ni++) {
            int col = col0 + wc * 64 + ni * 16 + lane15;
            float bcol = bias[col];
#pragma unroll
            for (int r = 0; r < 4; r++) {
                int row = row0 + wr * 32 + mi * 16 + quad * 4 + r;
                float u = acc[mi][ni][r] + bcol;
                if (act == 1) u = gelu_exact(u);
                C[(size_t)row * N + col] = u;
            }
        }
    }
}

// ---------------- attention v6: flash-style MFMA (bf16x3), block=(b,h,quarter) ----------------
// 512 blocks, 256 threads (4 waves), wave owns 32 q-rows = 2 subtiles of 16.
// m processed in 4 tiles of 128 with online softmax. Fragment conventions identical to
// gemm_mfma (R8-verified): A/B frags us8 over k at [outer=lane15][k=quad*8+j];
// D row=quad*4+r, col=lane15. Edge bias scattered into per-wave LDS S-buffer.

#define SBP 136  // S-buffer / VT pitch

__global__ __launch_bounds__(256, 2) void attn_kernel(const float* __restrict__ qkv,
                                                      const int* __restrict__ node_mask,
                                                      const int* __restrict__ offsets,
                                                      const int* __restrict__ elist,
                                                      const int* __restrict__ edge_index,
                                                      const int* __restrict__ edge_type,
                                                      const float* __restrict__ edge_weight,
                                                      const float* __restrict__ et_emb,
                                                      float* __restrict__ outbuf) {
    int bid = blockIdx.x;            // b*32 + h*4 + quarter
    int quarter = bid & 3;
    int h = (bid >> 2) & 7;
    int b = bid >> 5;
    int t = threadIdx.x;
    int w = t >> 6, L = t & 63;
    int quad = L >> 4, lane15 = L & 15;
    int q8 = quad * 8;

    __shared__ u16 sKh[128 * 40];     // K tile [m][d] hi
    __shared__ u16 sKl[128 * 40];     // lo
    __shared__ u16 sVh[32 * SBP];     // V^T tile [d][m] hi
    __shared__ u16 sVl[32 * SBP];     // lo
    __shared__ float sS[4 * 16 * SBP];  // per-wave S buffer

    float* Sw = &sS[w * 16 * SBP];
    const float scale = 0.17677669529663687f;  // 1/sqrt(32)
    int nbase = quarter * 128 + w * 32;

    // Q fragments (A-layout), split hi/lo, loaded once
    us8 Qh[2], Ql[2];
#pragma unroll
    for (int sub = 0; sub < 2; sub++) {
        size_t row = (size_t)(b * Nn + nbase + sub * 16 + lane15);
        float4 qa = *(const float4*)&qkv[row * 768 + h * HD + q8];
        float4 qb = *(const float4*)&qkv[row * 768 + h * HD + q8 + 4];
        float qv[8] = {qa.x, qa.y, qa.z, qa.w, qb.x, qb.y, qb.z, qb.w};
#pragma unroll
        for (int j = 0; j < 8; j++) {
            float xq = qv[j] * scale;
            u16 hh = f2bf(xq);
            Qh[sub][j] = hh;
            Ql[sub][j] = f2bf(xq - bf2f(hh));
        }
    }

    float Mst[2] = {-INFINITY, -INFINITY};
    float Lst[2] = {0.0f, 0.0f};
    f32x4 O[2][2];
#pragma unroll
    for (int sub = 0; sub < 2; sub++)
#pragma unroll
        for (int dc = 0; dc < 2; dc++) O[sub][dc] = {0.f, 0.f, 0.f, 0.f};

    for (int T = 0; T < 4; T++) {
        int m0 = T * 128;
        __syncthreads();  // prior tile's LDS reads complete
        for (int i = t; i < 128 * 32; i += 256) {
            int m = i >> 5, d = i & 31;
            size_t grow = (size_t)(b * Nn + m0 + m) * 768 + h * HD + d;
            float kf = qkv[grow + 256];
            u16 kh = f2bf(kf);
            sKh[m * 40 + d] = kh;
            sKl[m * 40 + d] = f2bf(kf - bf2f(kh));
            float vf = qkv[grow + 512];
            u16 vh = f2bf(vf);
            sVh[d * SBP + m] = vh;
            sVl[d * SBP + m] = f2bf(vf - bf2f(vh));
        }
        __syncthreads();

        // mask regs for owned m columns
        float mk[4][8];
#pragma unroll
        for (int c = 0; c < 4; c++) {
            int4 u0 = *(const int4*)&node_mask[b * Nn + m0 + c * 32 + q8];
            int4 u1 = *(const int4*)&node_mask[b * Nn + m0 + c * 32 + q8 + 4];
            mk[c][0] = u0.x ? 0.f : -INFINITY;
            mk[c][1] = u0.y ? 0.f : -INFINITY;
            mk[c][2] = u0.z ? 0.f : -INFINITY;
            mk[c][3] = u0.w ? 0.f : -INFINITY;
            mk[c][4] = u1.x ? 0.f : -INFINITY;
            mk[c][5] = u1.y ? 0.f : -INFINITY;
            mk[c][6] = u1.z ? 0.f : -INFINITY;
            mk[c][7] = u1.w ? 0.f : -INFINITY;
        }

#pragma unroll
        for (int sub = 0; sub < 2; sub++) {
            int nsub = nbase + sub * 16;
            bf16x8 qh = *(const bf16x8*)&Qh[sub];
            bf16x8 ql = *(const bf16x8*)&Ql[sub];

            // S = Q K^T (3-term split), 8 m-frags of 16
            f32x4 accS[8];
#pragma unroll
            for (int mc = 0; mc < 8; mc++) accS[mc] = {0.f, 0.f, 0.f, 0.f};
#pragma unroll
            for (int mc = 0; mc < 8; mc++) {
                us8 khr = *(const us8*)&sKh[(mc * 16 + lane15) * 40 + q8];
                us8 klr = *(const us8*)&sKl[(mc * 16 + lane15) * 40 + q8];
                bf16x8 kh = *(const bf16x8*)&khr;
                bf16x8 kl = *(const bf16x8*)&klr;
                accS[mc] = __builtin_amdgcn_mfma_f32_16x16x32_bf16(qh, kh, accS[mc], 0, 0, 0);
                accS[mc] = __builtin_amdgcn_mfma_f32_16x16x32_bf16(qh, kl, accS[mc], 0, 0, 0);
                accS[mc] = __builtin_amdgcn_mfma_f32_16x16x32_bf16(ql, kh, accS[mc], 0, 0, 0);
            }
            // D-layout -> S buffer
#pragma unroll
            for (int mc = 0; mc < 8; mc++)
#pragma unroll
                for (int r = 0; r < 4; r++)
                    Sw[(quad * 4 + r) * SBP + mc * 16 + lane15] = accS[mc][r];
            asm volatile("s_waitcnt lgkmcnt(0)" ::: "memory");

            // edge bias scatter (rows nsub..nsub+15, dst in this m-tile)
            int beg = offsets[b * Nn + nsub];
            int end = offsets[b * Nn + nsub + 16];
            for (int i = beg + L; i < end; i += 64) {
                int ge = elist[i];
                int e = ge & (Ee - 1);
                int dst = edge_index[b * 2 * Ee + Ee + e];
                if (dst >= m0 && dst < m0 + 128) {
                    int src = edge_index[b * 2 * Ee + e];
                    int ty = edge_type[b * Ee + e];
                    float wgt = edge_weight[b * Ee + e];
                    float val = et_emb[ty * Hh + h] + (ty == 2 ? wgt : 0.0f);
                    atomicAdd(&Sw[(src - nsub) * SBP + (dst - m0)], val);
                }
            }
            asm volatile("s_waitcnt lgkmcnt(0)" ::: "memory");

            // readback in A-layout rows (lane15 = row), + mask + online softmax
            float s[4][8];
#pragma unroll
            for (int c = 0; c < 4; c++) {
                float4 a = *(const float4*)&Sw[lane15 * SBP + c * 32 + q8];
                float4 bq = *(const float4*)&Sw[lane15 * SBP + c * 32 + q8 + 4];
                s[c][0] = a.x + mk[c][0];  s[c][1] = a.y + mk[c][1];
                s[c][2] = a.z + mk[c][2];  s[c][3] = a.w + mk[c][3];
                s[c][4] = bq.x + mk[c][4]; s[c][5] = bq.y + mk[c][5];
                s[c][6] = bq.z + mk[c][6]; s[c][7] = bq.w + mk[c][7];
            }
            float mx = s[0][0];
#pragma unroll
            for (int c = 0; c < 4; c++)
#pragma unroll
                for (int j = 0; j < 8; j++) mx = fmaxf(mx, s[c][j]);
            mx = fmaxf(mx, __shfl_xor(mx, 16));
            mx = fmaxf(mx, __shfl_xor(mx, 32));
            float Mnew = fmaxf(Mst[sub], mx);
            float alpha = __expf(Mst[sub] - Mnew);
            float rs = 0.0f;
#pragma unroll
            for (int c = 0; c < 4; c++)
#pragma unroll
                for (int j = 0; j < 8; j++) {
                    s[c][j] = __expf(s[c][j] - Mnew);
                    rs += s[c][j];
                }
            rs += __shfl_xor(rs, 16);
            rs += __shfl_xor(rs, 32);
            Lst[sub] = Lst[sub] * alpha + rs;
            Mst[sub] = Mnew;

            // P split to A-frags
            us8 Ph[4], Pl[4];
#pragma unroll
            for (int c = 0; c < 4; c++)
#pragma unroll
                for (int j = 0; j < 8; j++) {
                    u16 ph = f2bf(s[c][j]);
                    Ph[c][j] = ph;
                    Pl[c][j] = f2bf(s[c][j] - bf2f(ph));
                }

            // rescale O by alpha (alpha lives at lanes lane15==row; D-layout row=quad*4+r)
            float aD[4];
#pragma unroll
            for (int r = 0; r < 4; r++) aD[r] = __shfl(alpha, (L & 48) | (quad * 4 + r));
#pragma unroll
            for (int dc = 0; dc < 2; dc++)
#pragma unroll
                for (int r = 0; r < 4; r++) O[sub][dc][r] *= aD[r];

            // O += P V (3-term split)
#pragma unroll
            for (int c = 0; c < 4; c++) {
                bf16x8 ph = *(const bf16x8*)&Ph[c];
                bf16x8 pl = *(const bf16x8*)&Pl[c];
#pragma unroll
                for (int dc = 0; dc < 2; dc++) {
                    us8 vhr = *(const us8*)&sVh[(dc * 16 + lane15) * SBP + c * 32 + q8];
                    us8 vlr = *(const us8*)&sVl[(dc * 16 + lane15) * SBP + c * 32 + q8];
                    bf16x8 vh = *(const bf16x8*)&vhr;
                    bf16x8 vl = *(const bf16x8*)&vlr;
                    O[sub][dc] = __builtin_amdgcn_mfma_f32_16x16x32_bf16(ph, vh, O[sub][dc], 0, 0, 0);
                    O[sub][dc] = __builtin_amdgcn_mfma_f32_16x16x32_bf16(ph, vl, O[sub][dc], 0, 0, 0);
                    O[sub][dc] = __builtin_amdgcn_mfma_f32_16x16x32_bf16(pl, vh, O[sub][dc], 0, 0, 0);
                }
            }
        }
    }

    // finalize: divide by l, write out (D-layout)
#pragma unroll
    for (int sub = 0; sub < 2; sub++) {
        float linv = 1.0f / Lst[sub];
        float lD[4];
#pragma unroll
        for (int r = 0; r < 4; r++) lD[r] = __shfl(linv, (L & 48) | (quad * 4 + r));
#pragma unroll
        for (int dc = 0; dc < 2; dc++)
#pragma unroll
            for (int r = 0; r < 4; r++) {
                int row = nbase + sub * 16 + quad * 4 + r;
                outbuf[(size_t)(b * Nn + row) * Dd + h * HD + dc * 16 + lane15] =
                    O[sub][dc][r] * lD[r];
            }
    }
}

// ---------------- residual + LayerNorm ----------------

__global__ __launch_bounds__(256) void ln_kernel(float* __restrict__ x,
                                                 const float* __restrict__ res,
                                                 const float* __restrict__ g,
                                                 const float* __restrict__ bta) {
    int row = blockIdx.x;
    int t = threadIdx.x;
    __shared__ float red[4];
    __shared__ float stats[2];
    size_t idx = (size_t)row * Dd + t;
    float v = x[idx] + res[idx];
    float sm = v;
    for (int o = 32; o > 0; o >>= 1) sm += __shfl_down(sm, o);
    if ((t & 63) == 0) red[t >> 6] = sm;
    __syncthreads();
    if (t == 0) stats[0] = (red[0] + red[1] + red[2] + red[3]) * (1.0f / Dd);
    __syncthreads();
    float mu = stats[0];
    float dv = v - mu;
    float s2 = dv * dv;
    for (int o = 32; o > 0; o >>= 1) s2 += __shfl_down(s2, o);
    if ((t & 63) == 0) red[t >> 6] = s2;
    __syncthreads();
    if (t == 0) stats[1] = 1.0f / sqrtf((red[0] + red[1] + red[2] + red[3]) * (1.0f / Dd) + 1e-5f);
    __syncthreads();
    x[idx] = dv * stats[1] * g[t] + bta[t];
}

// ---------------- head ----------------

__global__ __launch_bounds__(256) void pool_kernel(const float* __restrict__ x,
                                                   const int* __restrict__ text_mask,
                                                   const int* __restrict__ image_mask,
                                                   float* __restrict__ pools) {
    int b = blockIdx.y;
    int n0 = blockIdx.x * 32;
    int t = threadIdx.x;
    float tp = 0.0f, ip = 0.0f, c1 = 0.0f, c2 = 0.0f;
    for (int n = n0; n < n0 + 32; n++) {
        float xv = x[(size_t)(b * Nn + n) * Dd + t];
        int tm = text_mask[b * Nn + n];
        int im = image_mask[b * Nn + n];
        tp += tm ? xv : 0.0f;
        ip += im ? xv : 0.0f;
        c1 += (float)tm;
        c2 += (float)im;
    }
    atomicAdd(&pools[b * 514 + t], tp);
    atomicAdd(&pools[b * 514 + 256 + t], ip);
    if (t == 0) {
        atomicAdd(&pools[b * 514 + 512], c1);
        atomicAdd(&pools[b * 514 + 513], c2);
    }
}

__global__ __launch_bounds__(256) void comb_kernel(const float* __restrict__ x,
                                                   const float* __restrict__ pools,
                                                   const int* __restrict__ gidx,
                                                   float* __restrict__ comb) {
    int b = blockIdx.x;
    int t = threadIdx.x;
    __shared__ float redd[12];
    float tc = fmaxf(pools[b * 514 + 512], 1.0f);
    float ic = fmaxf(pools[b * 514 + 513], 1.0f);
    float tp = pools[b * 514 + t] / tc;
    float ip = pools[b * 514 + 256 + t] / ic;
    int gi = gidx[b];
    comb[b * 776 + t] = x[(size_t)(b * Nn + gi) * Dd + t];
    comb[b * 776 + 256 + t] = tp;
    comb[b * 776 + 512 + t] = ip;
    float dotv = tp * ip, n1v = tp * tp, n2v = ip * ip;
    for (int o = 32; o > 0; o >>= 1) {
        dotv += __shfl_down(dotv, o);
        n1v += __shfl_down(n1v, o);
        n2v += __shfl_down(n2v, o);
    }
    if ((t & 63) == 0) { redd[t >> 6] = dotv; redd[4 + (t >> 6)] = n1v; redd[8 + (t >> 6)] = n2v; }
    __syncthreads();
    if (t == 0) {
        float dd = redd[0] + redd[1] + redd[2] + redd[3];
        float a1 = fmaxf(sqrtf(redd[4] + redd[5] + redd[6] + redd[7]), 1e-6f);
        float a2 = fmaxf(sqrtf(redd[8] + redd[9] + redd[10] + redd[11]), 1e-6f);
        comb[b * 776 + 768] = 1.0f - dd / (a1 * a2);
    }
}

__global__ __launch_bounds__(256) void h1_kernel(const float* __restrict__ comb,
                                                 const float* __restrict__ Wm1,
                                                 const float* __restrict__ bm1,
                                                 float* __restrict__ h1) {
    int b = blockIdx.y;
    int jc = blockIdx.x;
    int t = threadIdx.x;
    __shared__ float scomb[776];
    __shared__ float partial[2][128];
    for (int i = t; i < 769; i += 256) scomb[i] = comb[b * 776 + i];
    __syncthreads();
    int j = jc * 128 + (t & 127);
    int kh = t >> 7;
    int kbeg = kh ? 384 : 0;
    int kend = kh ? 769 : 384;
    float acc = 0.0f;
#pragma unroll 8
    for (int k = kbeg; k < kend; k++) acc += scomb[k] * Wm1[k * 512 + j];
    partial[kh][t & 127] = acc;
    __syncthreads();
    if (t < 128) {
        float v = partial[0][t] + partial[1][t] + bm1[jc * 128 + t];
        h1[b * 512 + jc * 128 + t] = gelu_exact(v);
    }
}

__global__ __launch_bounds__(256) void head_fin(const float* __restrict__ h1,
                                                const float* __restrict__ Wm2,
                                                const float* __restrict__ bm2,
                                                const float* __restrict__ Wm3,
                                                const float* __restrict__ bm3,
                                                float* __restrict__ out) {
    int b = blockIdx.x;
    int t = threadIdx.x;
    __shared__ float h1s[512];
    __shared__ float red[4];
    for (int i = t; i < 512; i += 256) h1s[i] = h1[b * 512 + i];
    __syncthreads();
    float acc = bm2[t];
#pragma unroll 8
    for (int k = 0; k < 512; k++) acc += h1s[k] * Wm2[k * 256 + t];
    float h2 = gelu_exact(acc);
    float lv = h2 * Wm3[t];
    for (int o = 32; o > 0; o >>= 1) lv += __shfl_down(lv, o);
    if ((t & 63) == 0) red[t >> 6] = lv;
    __syncthreads();
    if (t == 0) out[b] = red[0] + red[1] + red[2] + red[3] + bm3[0];
}

// ---------------- launch ----------------

#define OFF_IN  0
#define OFF_QKV 196608
#define OFF_O   786432
#define OFF_F1  983040
#define OFF_F2  1769472
#define W_TOTAL 2555904

extern "C" void kernel_launch(void* const* d_in, const int* in_sizes, int n_in,
                              void* d_out, int out_size, void* d_ws, size_t ws_size,
                              hipStream_t stream) {
    const float* node_feats = (const float*)d_in[0];
    const int* node_mask = (const int*)d_in[1];
    const int* text_mask = (const int*)d_in[2];
    const int* image_mask = (const int*)d_in[3];
    const int* gidx = (const int*)d_in[4];
    const int* edge_index = (const int*)d_in[5];
    const int* edge_type = (const int*)d_in[6];
    const float* edge_weight = (const float*)d_in[7];
    const float* W_in = (const float*)d_in[8];
    const float* b_in = (const float*)d_in[9];
    const float* Wqkv = (const float*)d_in[10];
    const float* bqkv = (const float*)d_in[11];
    const float* Wo = (const float*)d_in[12];
    const float* bo = (const float*)d_in[13];
    const float* ln1_g = (const float*)d_in[14];
    const float* ln1_b = (const float*)d_in[15];
    const float* ln2_g = (const float*)d_in[16];
    const float* ln2_b = (const float*)d_in[17];
    const float* Wff1 = (const float*)d_in[18];
    const float* bff1 = (const float*)d_in[19];
    const float* Wff2 = (const float*)d_in[20];
    const float* bff2 = (const float*)d_in[21];
    const float* et_emb = (const float*)d_in[22];
    const float* Wm1 = (const float*)d_in[23];
    const float* bm1 = (const float*)d_in[24];
    const float* Wm2 = (const float*)d_in[25];
    const float* bm2 = (const float*)d_in[26];
    const float* Wm3 = (const float*)d_in[27];
    const float* bm3 = (const float*)d_in[28];

    const int M = Bb * Nn; // 8192
    char* ws = (char*)d_ws;
    size_t off = 0;
    auto alloc = [&](size_t bytes) {
        void* p = ws + off;
        off += (bytes + 255) & ~(size_t)255;
        return p;
    };
    float* x = (float*)alloc((size_t)M * Dd * 4);
    float* qkvb = (float*)alloc((size_t)M * FF * 4);
    float* ffb = qkvb;
    float* attnout = (float*)alloc((size_t)M * Dd * 4);
    float* projb = (float*)alloc((size_t)M * Dd * 4);
    int* counts = (int*)alloc(8192 * 4);
    int* offsets = (int*)alloc(8193 * 4);
    int* cursor = (int*)alloc(8192 * 4);
    int* elist = (int*)alloc((size_t)Bb * Ee * 4);
    float* pools = (float*)alloc((size_t)Bb * 514 * 4);
    float* comb = (float*)alloc((size_t)Bb * 776 * 4);
    float* h1 = (float*)alloc((size_t)Bb * 512 * 4);
    u16* wh = (u16*)alloc((size_t)W_TOTAL * 2);
    u16* wl = (u16*)alloc((size_t)W_TOTAL * 2);
    (void)ws_size;

    zero_kernel<<<32, 256, 0, stream>>>(counts, 8192);
    zero_kernel<<<(Bb * 514 + 255) / 256, 256, 0, stream>>>((int*)pools, Bb * 514);
    count_kernel<<<256, 256, 0, stream>>>(edge_index, counts);
    scan_kernel<<<1, 1024, 0, stream>>>(counts, offsets, cursor);
    scatter_kernel<<<256, 256, 0, stream>>>(edge_index, cursor, elist);

    wsplit<<<dim3(1, 96, 1), 256, 0, stream>>>(W_in, wh + OFF_IN, wl + OFF_IN, 768, 256);
    wsplit<<<dim3(3, 32, 3), 256, 0, stream>>>(Wqkv, wh + OFF_QKV, wl + OFF_QKV, 256, 768);
    wsplit<<<dim3(1, 32, 3), 256, 0, stream>>>(Wo, wh + OFF_O, wl + OFF_O, 256, 256);
    wsplit<<<dim3(4, 32, 3), 256, 0, stream>>>(Wff1, wh + OFF_F1, wl + OFF_F1, 256, 1024);
    wsplit<<<dim3(1, 128, 3), 256, 0, stream>>>(Wff2, wh + OFF_F2, wl + OFF_F2, 1024, 256);

    gemm_mfma<<<dim3(Dd / 128, M / 64), 256, 0, stream>>>(
        node_feats, wh + OFF_IN, wl + OFF_IN, b_in, x, M, INDIM, Dd, 0);

    for (int l = 0; l < Ll; l++) {
        gemm_mfma<<<dim3(768 / 128, M / 64), 256, 0, stream>>>(
            x, wh + OFF_QKV + (size_t)l * 196608, wl + OFF_QKV + (size_t)l * 196608,
            bqkv + l * 768, qkvb, M, Dd, 768, 0);
        attn_kernel<<<Bb * Hh * 4, 256, 0, stream>>>(
            qkvb, node_mask, offsets, elist, edge_index, edge_type, edge_weight, et_emb, attnout);
        gemm_mfma<<<dim3(Dd / 128, M / 64), 256, 0, stream>>>(
            attnout, wh + OFF_O + (size_t)l * 65536, wl + OFF_O + (size_t)l * 65536,
            bo + l * Dd, projb, M, Dd, Dd, 0);
        ln_kernel<<<M, 256, 0, stream>>>(x, projb, ln1_g + l * Dd, ln1_b + l * Dd);
        gemm_mfma<<<dim3(FF / 128, M / 64), 256, 0, stream>>>(
            x, wh + OFF_F1 + (size_t)l * 262144, wl + OFF_F1 + (size_t)l * 262144,
            bff1 + l * FF, ffb, M, Dd, FF, 1);
        gemm_mfma<<<dim3(Dd / 128, M / 64), 256, 0, stream>>>(
            ffb, wh + OFF_F2 + (size_t)l * 262144, wl + OFF_F2 + (size_t)l * 262144,
            bff2 + l * Dd, projb, M, FF, Dd, 0);
        ln_kernel<<<M, 256, 0, stream>>>(x, projb, ln2_g + l * Dd, ln2_b + l * Dd);
    }

    pool_kernel<<<dim3(16, Bb), 256, 0, stream>>>(x, text_mask, image_mask, pools);
    comb_kernel<<<Bb, 256, 0, stream>>>(x, pools, gidx, comb);
    h1_kernel<<<dim3(4, Bb), 256, 0, stream>>>(comb, Wm1, bm1, h1);
    head_fin<<<Bb, 256, 0, stream>>>(h1, Wm2, bm2, Wm3, bm3, (float*)d_out);
}

// Round 10
// 705.007 us; speedup vs baseline: 2.0560x; 1.0022x over previous
//
#include <hip/hip_runtime.h>
#include <hip/hip_bf16.h>
#include <math.h>

#define Bb 16
#define Nn 512
#define Dd 256
#define Hh 8
#define HD 32
#define Ll 3
#define INDIM 768
#define Ee 4096
#define FF 1024
#define KP 40    // gemm LDS k-pitch in shorts (32 + 8 pad)

typedef unsigned short u16;
typedef __bf16 bf16x8 __attribute__((ext_vector_type(8)));
typedef float f32x4 __attribute__((ext_vector_type(4)));
typedef u16 us8 __attribute__((ext_vector_type(8)));
typedef u16 us4 __attribute__((ext_vector_type(4)));

__device__ __forceinline__ float gelu_exact(float x) {
    return 0.5f * x * (1.0f + erff(x * 0.70710678118654752f));
}

__device__ __forceinline__ u16 f2bf(float x) {
    unsigned int u = __float_as_uint(x);
    return (u16)((u + 0x7FFFu + ((u >> 16) & 1u)) >> 16);
}
__device__ __forceinline__ float bf2f(u16 h) {
    return __uint_as_float(((unsigned int)h) << 16);
}

// ---------------- edge bucketing ----------------

__global__ __launch_bounds__(256) void zero_kernel(int* __restrict__ p, int n) {
    int gid = blockIdx.x * 256 + threadIdx.x;
    if (gid < n) p[gid] = 0;
}

__global__ __launch_bounds__(256) void count_kernel(const int* __restrict__ edge_index,
                                                    int* __restrict__ counts) {
    int gid = blockIdx.x * 256 + threadIdx.x; // B*E = 65536
    int b = gid >> 12;
    int e = gid & (Ee - 1);
    int src = edge_index[b * 2 * Ee + e];
    atomicAdd(&counts[b * Nn + src], 1);
}

__global__ __launch_bounds__(1024) void scan_kernel(const int* __restrict__ counts,
                                                    int* __restrict__ offsets,
                                                    int* __restrict__ cursor) {
    __shared__ int ssum[1024];
    int t = threadIdx.x;
    int local[8];
    int s = 0;
#pragma unroll
    for (int i = 0; i < 8; i++) { local[i] = counts[t * 8 + i]; s += local[i]; }
    ssum[t] = s;
    __syncthreads();
    for (int off = 1; off < 1024; off *= 2) {
        __syncthreads();
        int v = (t >= off) ? ssum[t - off] : 0;
        __syncthreads();
        ssum[t] += v;
    }
    __syncthreads();
    int base = (t > 0) ? ssum[t - 1] : 0;
#pragma unroll
    for (int i = 0; i < 8; i++) {
        offsets[t * 8 + i] = base;
        cursor[t * 8 + i] = base;
        base += local[i];
    }
    if (t == 1023) offsets[8192] = base;
}

__global__ __launch_bounds__(256) void scatter_kernel(const int* __restrict__ edge_index,
                                                      int* __restrict__ cursor,
                                                      int* __restrict__ elist) {
    int gid = blockIdx.x * 256 + threadIdx.x;
    int b = gid >> 12;
    int e = gid & (Ee - 1);
    int src = edge_index[b * 2 * Ee + e];
    int pos = atomicAdd(&cursor[b * Nn + src], 1);
    elist[pos] = gid;
}

// ---------------- weight split+transpose: W[K][N] fp32 -> Wh,Wl [N][K] bf16 ----------------

__global__ __launch_bounds__(256) void wsplit(const float* __restrict__ W,
                                              u16* __restrict__ Wh,
                                              u16* __restrict__ Wl,
                                              int K, int N) {
    size_t moff = (size_t)blockIdx.z * K * N;
    const float* Ws = W + moff;
    u16* Whs = Wh + moff;
    u16* Wls = Wl + moff;
    int n = blockIdx.x * 256 + threadIdx.x;
    int k0 = blockIdx.y * 8;
    float w[8];
#pragma unroll
    for (int i = 0; i < 8; i++) w[i] = Ws[(size_t)(k0 + i) * N + n];
    u16 h[8], l[8];
#pragma unroll
    for (int i = 0; i < 8; i++) {
        h[i] = f2bf(w[i]);
        l[i] = f2bf(w[i] - bf2f(h[i]));
    }
    us8 hv = {h[0], h[1], h[2], h[3], h[4], h[5], h[6], h[7]};
    us8 lv = {l[0], l[1], l[2], l[3], l[4], l[5], l[6], l[7]};
    *(us8*)&Whs[(size_t)n * K + k0] = hv;
    *(us8*)&Wls[(size_t)n * K + k0] = lv;
}

// ---------------- MFMA GEMM 64x128 (bf16x3 split) — for N=256 shapes ----------------

__global__ __launch_bounds__(256) void gemm_mfma(const float* __restrict__ A,
                                                 const u16* __restrict__ Bh,
                                                 const u16* __restrict__ Bl,
                                                 const float* __restrict__ bias,
                                                 float* __restrict__ C,
                                                 int M, int K, int N, int act) {
    __shared__ u16 sAh[64 * KP];
    __shared__ u16 sAl[64 * KP];
    __shared__ u16 sBh[128 * KP];
    __shared__ u16 sBl[128 * KP];

    int t = threadIdx.x;
    int w = t >> 6, L = t & 63;
    int wr = w >> 1, wc = w & 1;
    int lane15 = L & 15, quad = L >> 4;
    int row0 = blockIdx.y * 64, col0 = blockIdx.x * 128;

    f32x4 acc[2][4];
#pragma unroll
    for (int mi = 0; mi < 2; mi++)
#pragma unroll
        for (int ni = 0; ni < 4; ni++) acc[mi][ni] = {0.f, 0.f, 0.f, 0.f};

    int ar0 = t >> 3, akq0 = (t & 7) * 4;
    int ar1 = (t + 256) >> 3, akq1 = akq0;
    int bn0 = t >> 2, bk0 = (t & 3) * 8;
    int bn1 = (t + 256) >> 2, bk1 = bk0;

    const float* Ap0 = &A[(size_t)(row0 + ar0) * K + akq0];
    const float* Ap1 = &A[(size_t)(row0 + ar1) * K + akq1];
    const u16* Bhp0 = &Bh[(size_t)(col0 + bn0) * K + bk0];
    const u16* Bhp1 = &Bh[(size_t)(col0 + bn1) * K + bk1];
    const u16* Blp0 = &Bl[(size_t)(col0 + bn0) * K + bk0];
    const u16* Blp1 = &Bl[(size_t)(col0 + bn1) * K + bk1];

    float4 av0 = *(const float4*)&Ap0[0];
    float4 av1 = *(const float4*)&Ap1[0];
    us8 bhv0 = *(const us8*)&Bhp0[0];
    us8 bhv1 = *(const us8*)&Bhp1[0];
    us8 blv0 = *(const us8*)&Blp0[0];
    us8 blv1 = *(const us8*)&Blp1[0];

    for (int k0 = 0; k0 < K; k0 += 32) {
        __syncthreads();
        {
            float a[4] = {av0.x, av0.y, av0.z, av0.w};
            u16 h[4], l[4];
#pragma unroll
            for (int i = 0; i < 4; i++) { h[i] = f2bf(a[i]); l[i] = f2bf(a[i] - bf2f(h[i])); }
            us4 hv = {h[0], h[1], h[2], h[3]};
            us4 lv = {l[0], l[1], l[2], l[3]};
            *(us4*)&sAh[ar0 * KP + akq0] = hv;
            *(us4*)&sAl[ar0 * KP + akq0] = lv;
        }
        {
            float a[4] = {av1.x, av1.y, av1.z, av1.w};
            u16 h[4], l[4];
#pragma unroll
            for (int i = 0; i < 4; i++) { h[i] = f2bf(a[i]); l[i] = f2bf(a[i] - bf2f(h[i])); }
            us4 hv = {h[0], h[1], h[2], h[3]};
            us4 lv = {l[0], l[1], l[2], l[3]};
            *(us4*)&sAh[ar1 * KP + akq1] = hv;
            *(us4*)&sAl[ar1 * KP + akq1] = lv;
        }
        *(us8*)&sBh[bn0 * KP + bk0] = bhv0;
        *(us8*)&sBh[bn1 * KP + bk1] = bhv1;
        *(us8*)&sBl[bn0 * KP + bk0] = blv0;
        *(us8*)&sBl[bn1 * KP + bk1] = blv1;
        __syncthreads();

        if (k0 + 32 < K) {
            av0 = *(const float4*)&Ap0[k0 + 32];
            av1 = *(const float4*)&Ap1[k0 + 32];
            bhv0 = *(const us8*)&Bhp0[k0 + 32];
            bhv1 = *(const us8*)&Bhp1[k0 + 32];
            blv0 = *(const us8*)&Blp0[k0 + 32];
            blv1 = *(const us8*)&Blp1[k0 + 32];
        }

        us8 ahr[2], alr[2], bhr[4], blr[4];
#pragma unroll
        for (int mi = 0; mi < 2; mi++) {
            int ro = (wr * 32 + mi * 16 + lane15) * KP + quad * 8;
            ahr[mi] = *(const us8*)&sAh[ro];
            alr[mi] = *(const us8*)&sAl[ro];
        }
#pragma unroll
        for (int ni = 0; ni < 4; ni++) {
            int ro = (wc * 64 + ni * 16 + lane15) * KP + quad * 8;
            bhr[ni] = *(const us8*)&sBh[ro];
            blr[ni] = *(const us8*)&sBl[ro];
        }
#pragma unroll
        for (int mi = 0; mi < 2; mi++) {
            bf16x8 ah = *(const bf16x8*)&ahr[mi];
            bf16x8 al = *(const bf16x8*)&alr[mi];
#pragma unroll
            for (int ni = 0; ni < 4; ni++) {
                bf16x8 bh = *(const bf16x8*)&bhr[ni];
                bf16x8 bl = *(const bf16x8*)&blr[ni];
                acc[mi][ni] = __builtin_amdgcn_mfma_f32_16x16x32_bf16(ah, bh, acc[mi][ni], 0, 0, 0);
                acc[mi][ni] = __builtin_amdgcn_mfma_f32_16x16x32_bf16(ah, bl, acc[mi][ni], 0, 0, 0);
                acc[mi][ni] = __builtin_amdgcn_mfma_f32_16x16x32_bf16(al, bh, acc[mi][ni], 0, 0, 0);
            }
        }
    }

#pragma unroll
    for (int mi = 0; mi < 2; mi++) {
#pragma unroll
        for (int ni = 0; ni < 4; ni++) {
            int col = col0 + wc * 64 + ni * 16 + lane15;
            float bcol = bias[col];
#pragma unroll
            for (int r = 0; r < 4; r++) {
                int row = row0 + wr * 32 + mi * 16 + quad * 4 + r;
                float u = acc[mi][ni][r] + bcol;
                if (act == 1) u = gelu_exact(u);
                C[(size_t)row * N + col] = u;
            }
        }
    }
}

// ---------------- MFMA GEMM 128x128 (bf16x3), wave tile 64x64 — for N>=768 shapes -----
// 48 MFMA per 16 b128 frag reads per wave per k-step (2x the 64x128 variant's ratio).

__global__ __launch_bounds__(256) void gemm_mfma128(const float* __restrict__ A,
                                                    const u16* __restrict__ Bh,
                                                    const u16* __restrict__ Bl,
                                                    const float* __restrict__ bias,
                                                    float* __restrict__ C,
                                                    int M, int K, int N, int act) {
    __shared__ u16 sAh[128 * KP];
    __shared__ u16 sAl[128 * KP];
    __shared__ u16 sBh[128 * KP];
    __shared__ u16 sBl[128 * KP];

    int t = threadIdx.x;
    int w = t >> 6, L = t & 63;
    int wr = w >> 1, wc = w & 1;
    int lane15 = L & 15, quad = L >> 4;
    int row0 = blockIdx.y * 128, col0 = blockIdx.x * 128;

    f32x4 acc[4][4];
#pragma unroll
    for (int mi = 0; mi < 4; mi++)
#pragma unroll
        for (int ni = 0; ni < 4; ni++) acc[mi][ni] = {0.f, 0.f, 0.f, 0.f};

    int ar0 = t >> 3, ak0 = (t & 7) * 4;    // A: 4 units, rows ar0+32i
    int bn0 = t >> 2, bk0 = (t & 3) * 8;    // B: 2 units, cols bn0+64i

    const float* Ap = &A[(size_t)(row0 + ar0) * K + ak0];
    const u16* Bhp = &Bh[(size_t)(col0 + bn0) * K + bk0];
    const u16* Blp = &Bl[(size_t)(col0 + bn0) * K + bk0];

    float4 av[4];
    us8 bhv[2], blv[2];
#pragma unroll
    for (int i = 0; i < 4; i++) av[i] = *(const float4*)&Ap[(size_t)(32 * i) * K];
#pragma unroll
    for (int i = 0; i < 2; i++) {
        bhv[i] = *(const us8*)&Bhp[(size_t)(64 * i) * K];
        blv[i] = *(const us8*)&Blp[(size_t)(64 * i) * K];
    }

    for (int k0 = 0; k0 < K; k0 += 32) {
        __syncthreads();
#pragma unroll
        for (int i = 0; i < 4; i++) {
            float a[4] = {av[i].x, av[i].y, av[i].z, av[i].w};
            u16 h[4], l[4];
#pragma unroll
            for (int j = 0; j < 4; j++) { h[j] = f2bf(a[j]); l[j] = f2bf(a[j] - bf2f(h[j])); }
            us4 hv = {h[0], h[1], h[2], h[3]};
            us4 lv = {l[0], l[1], l[2], l[3]};
            *(us4*)&sAh[(ar0 + 32 * i) * KP + ak0] = hv;
            *(us4*)&sAl[(ar0 + 32 * i) * KP + ak0] = lv;
        }
#pragma unroll
        for (int i = 0; i < 2; i++) {
            *(us8*)&sBh[(bn0 + 64 * i) * KP + bk0] = bhv[i];
            *(us8*)&sBl[(bn0 + 64 * i) * KP + bk0] = blv[i];
        }
        __syncthreads();

        if (k0 + 32 < K) {
#pragma unroll
            for (int i = 0; i < 4; i++) av[i] = *(const float4*)&Ap[(size_t)(32 * i) * K + k0 + 32];
#pragma unroll
            for (int i = 0; i < 2; i++) {
                bhv[i] = *(const us8*)&Bhp[(size_t)(64 * i) * K + k0 + 32];
                blv[i] = *(const us8*)&Blp[(size_t)(64 * i) * K + k0 + 32];
            }
        }

        us8 ahr[4], alr[4], bhr[4], blr[4];
#pragma unroll
        for (int mi = 0; mi < 4; mi++) {
            int ro = (wr * 64 + mi * 16 + lane15) * KP + quad * 8;
            ahr[mi] = *(const us8*)&sAh[ro];
            alr[mi] = *(const us8*)&sAl[ro];
        }
#pragma unroll
        for (int ni = 0; ni < 4; ni++) {
            int ro = (wc * 64 + ni * 16 + lane15) * KP + quad * 8;
            bhr[ni] = *(const us8*)&sBh[ro];
            blr[ni] = *(const us8*)&sBl[ro];
        }
#pragma unroll
        for (int mi = 0; mi < 4; mi++) {
            bf16x8 ah = *(const bf16x8*)&ahr[mi];
            bf16x8 al = *(const bf16x8*)&alr[mi];
#pragma unroll
            for (int ni = 0; ni < 4; ni++) {
                bf16x8 bh = *(const bf16x8*)&bhr[ni];
                bf16x8 bl = *(const bf16x8*)&blr[ni];
                acc[mi][ni] = __builtin_amdgcn_mfma_f32_16x16x32_bf16(ah, bh, acc[mi][ni], 0, 0, 0);
                acc[mi][ni] = __builtin_amdgcn_mfma_f32_16x16x32_bf16(ah, bl, acc[mi][ni], 0, 0, 0);
                acc[mi][ni] = __builtin_amdgcn_mfma_f32_16x16x32_bf16(al, bh, acc[mi][ni], 0, 0, 0);
            }
        }
    }

#pragma unroll
    for (int mi = 0; mi < 4; mi++) {
#pragma unroll
        for (int ni = 0; ni < 4; ni++) {
            int col = col0 + wc * 64 + ni * 16 + lane15;
            float bcol = bias[col];
#pragma unroll
            for (int r = 0; r < 4; r++) {
                int row = row0 + wr * 64 + mi * 16 + quad * 4 + r;
                float u = acc[mi][ni][r] + bcol;
                if (act == 1) u = gelu_exact(u);
                C[(size_t)row * N + col] = u;
            }
        }
    }
}

// ---------------- attention v6: flash-style MFMA (bf16x3), block=(b,h,quarter) ----------------

#define SBP 132  // S-buffer / VT pitch (== 4 mod 32: conflict-free f32 S reads, 2-way writes)

__global__ __launch_bounds__(256, 2) void attn_kernel(const float* __restrict__ qkv,
                                                      const int* __restrict__ node_mask,
                                                      const int* __restrict__ offsets,
                                                      const int* __restrict__ elist,
                                                      const int* __restrict__ edge_index,
                                                      const int* __restrict__ edge_type,
                                                      const float* __restrict__ edge_weight,
                                                      const float* __restrict__ et_emb,
                                                      float* __restrict__ outbuf) {
    int bid = blockIdx.x;            // b*32 + h*4 + quarter
    int quarter = bid & 3;
    int h = (bid >> 2) & 7;
    int b = bid >> 5;
    int t = threadIdx.x;
    int w = t >> 6, L = t & 63;
    int quad = L >> 4, lane15 = L & 15;
    int q8 = quad * 8;

    __shared__ u16 sKh[128 * 40];
    __shared__ u16 sKl[128 * 40];
    __shared__ u16 sVh[32 * SBP];
    __shared__ u16 sVl[32 * SBP];
    __shared__ float sS[4 * 16 * SBP];

    float* Sw = &sS[w * 16 * SBP];
    const float scale = 0.17677669529663687f;
    int nbase = quarter * 128 + w * 32;

    us8 Qh[2], Ql[2];
#pragma unroll
    for (int sub = 0; sub < 2; sub++) {
        size_t row = (size_t)(b * Nn + nbase + sub * 16 + lane15);
        float4 qa = *(const float4*)&qkv[row * 768 + h * HD + q8];
        float4 qb = *(const float4*)&qkv[row * 768 + h * HD + q8 + 4];
        float qv[8] = {qa.x, qa.y, qa.z, qa.w, qb.x, qb.y, qb.z, qb.w};
#pragma unroll
        for (int j = 0; j < 8; j++) {
            float xq = qv[j] * scale;
            u16 hh = f2bf(xq);
            Qh[sub][j] = hh;
            Ql[sub][j] = f2bf(xq - bf2f(hh));
        }
    }

    float Mst[2] = {-INFINITY, -INFINITY};
    float Lst[2] = {0.0f, 0.0f};
    f32x4 O[2][2];
#pragma unroll
    for (int sub = 0; sub < 2; sub++)
#pragma unroll
        for (int dc = 0; dc < 2; dc++) O[sub][dc] = {0.f, 0.f, 0.f, 0.f};

    for (int T = 0; T < 4; T++) {
        int m0 = T * 128;
        __syncthreads();
        for (int i = t; i < 128 * 32; i += 256) {
            int m = i >> 5, d = i & 31;
            size_t grow = (size_t)(b * Nn + m0 + m) * 768 + h * HD + d;
            float kf = qkv[grow + 256];
            u16 kh = f2bf(kf);
            sKh[m * 40 + d] = kh;
            sKl[m * 40 + d] = f2bf(kf - bf2f(kh));
            float vf = qkv[grow + 512];
            u16 vh = f2bf(vf);
            sVh[d * SBP + m] = vh;
            sVl[d * SBP + m] = f2bf(vf - bf2f(vh));
        }
        __syncthreads();

        float mk[4][8];
#pragma unroll
        for (int c = 0; c < 4; c++) {
            int4 u0 = *(const int4*)&node_mask[b * Nn + m0 + c * 32 + q8];
            int4 u1 = *(const int4*)&node_mask[b * Nn + m0 + c * 32 + q8 + 4];
            mk[c][0] = u0.x ? 0.f : -INFINITY;
            mk[c][1] = u0.y ? 0.f : -INFINITY;
            mk[c][2] = u0.z ? 0.f : -INFINITY;
            mk[c][3] = u0.w ? 0.f : -INFINITY;
            mk[c][4] = u1.x ? 0.f : -INFINITY;
            mk[c][5] = u1.y ? 0.f : -INFINITY;
            mk[c][6] = u1.z ? 0.f : -INFINITY;
            mk[c][7] = u1.w ? 0.f : -INFINITY;
        }

#pragma unroll
        for (int sub = 0; sub < 2; sub++) {
            int nsub = nbase + sub * 16;
            bf16x8 qh = *(const bf16x8*)&Qh[sub];
            bf16x8 ql = *(const bf16x8*)&Ql[sub];

            f32x4 accS[8];
#pragma unroll
            for (int mc = 0; mc < 8; mc++) accS[mc] = {0.f, 0.f, 0.f, 0.f};
#pragma unroll
            for (int mc = 0; mc < 8; mc++) {
                us8 khr = *(const us8*)&sKh[(mc * 16 + lane15) * 40 + q8];
                us8 klr = *(const us8*)&sKl[(mc * 16 + lane15) * 40 + q8];
                bf16x8 kh = *(const bf16x8*)&khr;
                bf16x8 kl = *(const bf16x8*)&klr;
                accS[mc] = __builtin_amdgcn_mfma_f32_16x16x32_bf16(qh, kh, accS[mc], 0, 0, 0);
                accS[mc] = __builtin_amdgcn_mfma_f32_16x16x32_bf16(qh, kl, accS[mc], 0, 0, 0);
                accS[mc] = __builtin_amdgcn_mfma_f32_16x16x32_bf16(ql, kh, accS[mc], 0, 0, 0);
            }
#pragma unroll
            for (int mc = 0; mc < 8; mc++)
#pragma unroll
                for (int r = 0; r < 4; r++)
                    Sw[(quad * 4 + r) * SBP + mc * 16 + lane15] = accS[mc][r];
            asm volatile("s_waitcnt lgkmcnt(0)" ::: "memory");

            int beg = offsets[b * Nn + nsub];
            int end = offsets[b * Nn + nsub + 16];
            for (int i = beg + L; i < end; i += 64) {
                int ge = elist[i];
                int e = ge & (Ee - 1);
                int dst = edge_index[b * 2 * Ee + Ee + e];
                if (dst >= m0 && dst < m0 + 128) {
                    int src = edge_index[b * 2 * Ee + e];
                    int ty = edge_type[b * Ee + e];
                    float wgt = edge_weight[b * Ee + e];
                    float val = et_emb[ty * Hh + h] + (ty == 2 ? wgt : 0.0f);
                    atomicAdd(&Sw[(src - nsub) * SBP + (dst - m0)], val);
                }
            }
            asm volatile("s_waitcnt lgkmcnt(0)" ::: "memory");

            float s[4][8];
#pragma unroll
            for (int c = 0; c < 4; c++) {
                float4 a = *(const float4*)&Sw[lane15 * SBP + c * 32 + q8];
                float4 bq = *(const float4*)&Sw[lane15 * SBP + c * 32 + q8 + 4];
                s[c][0] = a.x + mk[c][0];  s[c][1] = a.y + mk[c][1];
                s[c][2] = a.z + mk[c][2];  s[c][3] = a.w + mk[c][3];
                s[c][4] = bq.x + mk[c][4]; s[c][5] = bq.y + mk[c][5];
                s[c][6] = bq.z + mk[c][6]; s[c][7] = bq.w + mk[c][7];
            }
            float mx = s[0][0];
#pragma unroll
            for (int c = 0; c < 4; c++)
#pragma unroll
                for (int j = 0; j < 8; j++) mx = fmaxf(mx, s[c][j]);
            mx = fmaxf(mx, __shfl_xor(mx, 16));
            mx = fmaxf(mx, __shfl_xor(mx, 32));
            float Mnew = fmaxf(Mst[sub], mx);
            float alpha = __expf(Mst[sub] - Mnew);
            float rs = 0.0f;
#pragma unroll
            for (int c = 0; c < 4; c++)
#pragma unroll
                for (int j = 0; j < 8; j++) {
                    s[c][j] = __expf(s[c][j] - Mnew);
                    rs += s[c][j];
                }
            rs += __shfl_xor(rs, 16);
            rs += __shfl_xor(rs, 32);
            Lst[sub] = Lst[sub] * alpha + rs;
            Mst[sub] = Mnew;

            us8 Ph[4], Pl[4];
#pragma unroll
            for (int c = 0; c < 4; c++)
#pragma unroll
                for (int j = 0; j < 8; j++) {
                    u16 ph = f2bf(s[c][j]);
                    Ph[c][j] = ph;
                    Pl[c][j] = f2bf(s[c][j] - bf2f(ph));
                }

            float aD[4];
#pragma unroll
            for (int r = 0; r < 4; r++) aD[r] = __shfl(alpha, (L & 48) | (quad * 4 + r));
#pragma unroll
            for (int dc = 0; dc < 2; dc++)
#pragma unroll
                for (int r = 0; r < 4; r++) O[sub][dc][r] *= aD[r];

#pragma unroll
            for (int c = 0; c < 4; c++) {
                bf16x8 ph = *(const bf16x8*)&Ph[c];
                bf16x8 pl = *(const bf16x8*)&Pl[c];
#pragma unroll
                for (int dc = 0; dc < 2; dc++) {
                    us8 vhr = *(const us8*)&sVh[(dc * 16 + lane15) * SBP + c * 32 + q8];
                    us8 vlr = *(const us8*)&sVl[(dc * 16 + lane15) * SBP + c * 32 + q8];
                    bf16x8 vh = *(const bf16x8*)&vhr;
                    bf16x8 vl = *(const bf16x8*)&vlr;
                    O[sub][dc] = __builtin_amdgcn_mfma_f32_16x16x32_bf16(ph, vh, O[sub][dc], 0, 0, 0);
                    O[sub][dc] = __builtin_amdgcn_mfma_f32_16x16x32_bf16(ph, vl, O[sub][dc], 0, 0, 0);
                    O[sub][dc] = __builtin_amdgcn_mfma_f32_16x16x32_bf16(pl, vh, O[sub][dc], 0, 0, 0);
                }
            }
        }
    }

#pragma unroll
    for (int sub = 0; sub < 2; sub++) {
        float linv = 1.0f / Lst[sub];
        float lD[4];
#pragma unroll
        for (int r = 0; r < 4; r++) lD[r] = __shfl(linv, (L & 48) | (quad * 4 + r));
#pragma unroll
        for (int dc = 0; dc < 2; dc++)
#pragma unroll
            for (int r = 0; r < 4; r++) {
                int row = nbase + sub * 16 + quad * 4 + r;
                outbuf[(size_t)(b * Nn + row) * Dd + h * HD + dc * 16 + lane15] =
                    O[sub][dc][r] * lD[r];
            }
    }
}

// ---------------- residual + LayerNorm ----------------

__global__ __launch_bounds__(256) void ln_kernel(float* __restrict__ x,
                                                 const float* __restrict__ res,
                                                 const float* __restrict__ g,
                                                 const float* __restrict__ bta) {
    int row = blockIdx.x;
    int t = threadIdx.x;
    __shared__ float red[4];
    __shared__ float stats[2];
    size_t idx = (size_t)row * Dd + t;
    float v = x[idx] + res[idx];
    float sm = v;
    for (int o = 32; o > 0; o >>= 1) sm += __shfl_down(sm, o);
    if ((t & 63) == 0) red[t >> 6] = sm;
    __syncthreads();
    if (t == 0) stats[0] = (red[0] + red[1] + red[2] + red[3]) * (1.0f / Dd);
    __syncthreads();
    float mu = stats[0];
    float dv = v - mu;
    float s2 = dv * dv;
    for (int o = 32; o > 0; o >>= 1) s2 += __shfl_down(s2, o);
    if ((t & 63) == 0) red[t >> 6] = s2;
    __syncthreads();
    if (t == 0) stats[1] = 1.0f / sqrtf((red[0] + red[1] + red[2] + red[3]) * (1.0f / Dd) + 1e-5f);
    __syncthreads();
    x[idx] = dv * stats[1] * g[t] + bta[t];
}

// ---------------- head ----------------

__global__ __launch_bounds__(256) void pool_kernel(const float* __restrict__ x,
                                                   const int* __restrict__ text_mask,
                                                   const int* __restrict__ image_mask,
                                                   float* __restrict__ pools) {
    int b = blockIdx.y;
    int n0 = blockIdx.x * 32;
    int t = threadIdx.x;
    float tp = 0.0f, ip = 0.0f, c1 = 0.0f, c2 = 0.0f;
    for (int n = n0; n < n0 + 32; n++) {
        float xv = x[(size_t)(b * Nn + n) * Dd + t];
        int tm = text_mask[b * Nn + n];
        int im = image_mask[b * Nn + n];
        tp += tm ? xv : 0.0f;
        ip += im ? xv : 0.0f;
        c1 += (float)tm;
        c2 += (float)im;
    }
    atomicAdd(&pools[b * 514 + t], tp);
    atomicAdd(&pools[b * 514 + 256 + t], ip);
    if (t == 0) {
        atomicAdd(&pools[b * 514 + 512], c1);
        atomicAdd(&pools[b * 514 + 513], c2);
    }
}

__global__ __launch_bounds__(256) void comb_kernel(const float* __restrict__ x,
                                                   const float* __restrict__ pools,
                                                   const int* __restrict__ gidx,
                                                   float* __restrict__ comb) {
    int b = blockIdx.x;
    int t = threadIdx.x;
    __shared__ float redd[12];
    float tc = fmaxf(pools[b * 514 + 512], 1.0f);
    float ic = fmaxf(pools[b * 514 + 513], 1.0f);
    float tp = pools[b * 514 + t] / tc;
    float ip = pools[b * 514 + 256 + t] / ic;
    int gi = gidx[b];
    comb[b * 776 + t] = x[(size_t)(b * Nn + gi) * Dd + t];
    comb[b * 776 + 256 + t] = tp;
    comb[b * 776 + 512 + t] = ip;
    float dotv = tp * ip, n1v = tp * tp, n2v = ip * ip;
    for (int o = 32; o > 0; o >>= 1) {
        dotv += __shfl_down(dotv, o);
        n1v += __shfl_down(n1v, o);
        n2v += __shfl_down(n2v, o);
    }
    if ((t & 63) == 0) { redd[t >> 6] = dotv; redd[4 + (t >> 6)] = n1v; redd[8 + (t >> 6)] = n2v; }
    __syncthreads();
    if (t == 0) {
        float dd = redd[0] + redd[1] + redd[2] + redd[3];
        float a1 = fmaxf(sqrtf(redd[4] + redd[5] + redd[6] + redd[7]), 1e-6f);
        float a2 = fmaxf(sqrtf(redd[8] + redd[9] + redd[10] + redd[11]), 1e-6f);
        comb[b * 776 + 768] = 1.0f - dd / (a1 * a2);
    }
}

__global__ __launch_bounds__(256) void h1_kernel(const float* __restrict__ comb,
                                                 const float* __restrict__ Wm1,
                                                 const float* __restrict__ bm1,
                                                 float* __restrict__ h1) {
    int b = blockIdx.y;
    int jc = blockIdx.x;
    int t = threadIdx.x;
    __shared__ float scomb[776];
    __shared__ float partial[2][128];
    for (int i = t; i < 769; i += 256) scomb[i] = comb[b * 776 + i];
    __syncthreads();
    int j = jc * 128 + (t & 127);
    int kh = t >> 7;
    int kbeg = kh ? 384 : 0;
    int kend = kh ? 769 : 384;
    float acc = 0.0f;
#pragma unroll 8
    for (int k = kbeg; k < kend; k++) acc += scomb[k] * Wm1[k * 512 + j];
    partial[kh][t & 127] = acc;
    __syncthreads();
    if (t < 128) {
        float v = partial[0][t] + partial[1][t] + bm1[jc * 128 + t];
        h1[b * 512 + jc * 128 + t] = gelu_exact(v);
    }
}

__global__ __launch_bounds__(256) void head_fin(const float* __restrict__ h1,
                                                const float* __restrict__ Wm2,
                                                const float* __restrict__ bm2,
                                                const float* __restrict__ Wm3,
                                                const float* __restrict__ bm3,
                                                float* __restrict__ out) {
    int b = blockIdx.x;
    int t = threadIdx.x;
    __shared__ float h1s[512];
    __shared__ float red[4];
    for (int i = t; i < 512; i += 256) h1s[i] = h1[b * 512 + i];
    __syncthreads();
    float acc = bm2[t];
#pragma unroll 8
    for (int k = 0; k < 512; k++) acc += h1s[k] * Wm2[k * 256 + t];
    float h2 = gelu_exact(acc);
    float lv = h2 * Wm3[t];
    for (int o = 32; o > 0; o >>= 1) lv += __shfl_down(lv, o);
    if ((t & 63) == 0) red[t >> 6] = lv;
    __syncthreads();
    if (t == 0) out[b] = red[0] + red[1] + red[2] + red[3] + bm3[0];
}

// ---------------- launch ----------------

#define OFF_IN  0
#define OFF_QKV 196608
#define OFF_O   786432
#define OFF_F1  983040
#define OFF_F2  1769472
#define W_TOTAL 2555904

extern "C" void kernel_launch(void* const* d_in, const int* in_sizes, int n_in,
                              void* d_out, int out_size, void* d_ws, size_t ws_size,
                              hipStream_t stream) {
    const float* node_feats = (const float*)d_in[0];
    const int* node_mask = (const int*)d_in[1];
    const int* text_mask = (const int*)d_in[2];
    const int* image_mask = (const int*)d_in[3];
    const int* gidx = (const int*)d_in[4];
    const int* edge_index = (const int*)d_in[5];
    const int* edge_type = (const int*)d_in[6];
    const float* edge_weight = (const float*)d_in[7];
    const float* W_in = (const float*)d_in[8];
    const float* b_in = (const float*)d_in[9];
    const float* Wqkv = (const float*)d_in[10];
    const float* bqkv = (const float*)d_in[11];
    const float* Wo = (const float*)d_in[12];
    const float* bo = (const float*)d_in[13];
    const float* ln1_g = (const float*)d_in[14];
    const float* ln1_b = (const float*)d_in[15];
    const float* ln2_g = (const float*)d_in[16];
    const float* ln2_b = (const float*)d_in[17];
    const float* Wff1 = (const float*)d_in[18];
    const float* bff1 = (const float*)d_in[19];
    const float* Wff2 = (const float*)d_in[20];
    const float* bff2 = (const float*)d_in[21];
    const float* et_emb = (const float*)d_in[22];
    const float* Wm1 = (const float*)d_in[23];
    const float* bm1 = (const float*)d_in[24];
    const float* Wm2 = (const float*)d_in[25];
    const float* bm2 = (const float*)d_in[26];
    const float* Wm3 = (const float*)d_in[27];
    const float* bm3 = (const float*)d_in[28];

    const int M = Bb * Nn; // 8192
    char* ws = (char*)d_ws;
    size_t off = 0;
    auto alloc = [&](size_t bytes) {
        void* p = ws + off;
        off += (bytes + 255) & ~(size_t)255;
        return p;
    };
    float* x = (float*)alloc((size_t)M * Dd * 4);
    float* qkvb = (float*)alloc((size_t)M * FF * 4);
    float* ffb = qkvb;
    float* attnout = (float*)alloc((size_t)M * Dd * 4);
    float* projb = (float*)alloc((size_t)M * Dd * 4);
    int* counts = (int*)alloc(8192 * 4);
    int* offsets = (int*)alloc(8193 * 4);
    int* cursor = (int*)alloc(8192 * 4);
    int* elist = (int*)alloc((size_t)Bb * Ee * 4);
    float* pools = (float*)alloc((size_t)Bb * 514 * 4);
    float* comb = (float*)alloc((size_t)Bb * 776 * 4);
    float* h1 = (float*)alloc((size_t)Bb * 512 * 4);
    u16* wh = (u16*)alloc((size_t)W_TOTAL * 2);
    u16* wl = (u16*)alloc((size_t)W_TOTAL * 2);
    (void)ws_size;

    zero_kernel<<<32, 256, 0, stream>>>(counts, 8192);
    zero_kernel<<<(Bb * 514 + 255) / 256, 256, 0, stream>>>((int*)pools, Bb * 514);
    count_kernel<<<256, 256, 0, stream>>>(edge_index, counts);
    scan_kernel<<<1, 1024, 0, stream>>>(counts, offsets, cursor);
    scatter_kernel<<<256, 256, 0, stream>>>(edge_index, cursor, elist);

    wsplit<<<dim3(1, 96, 1), 256, 0, stream>>>(W_in, wh + OFF_IN, wl + OFF_IN, 768, 256);
    wsplit<<<dim3(3, 32, 3), 256, 0, stream>>>(Wqkv, wh + OFF_QKV, wl + OFF_QKV, 256, 768);
    wsplit<<<dim3(1, 32, 3), 256, 0, stream>>>(Wo, wh + OFF_O, wl + OFF_O, 256, 256);
    wsplit<<<dim3(4, 32, 3), 256, 0, stream>>>(Wff1, wh + OFF_F1, wl + OFF_F1, 256, 1024);
    wsplit<<<dim3(1, 128, 3), 256, 0, stream>>>(Wff2, wh + OFF_F2, wl + OFF_F2, 1024, 256);

    gemm_mfma<<<dim3(Dd / 128, M / 64), 256, 0, stream>>>(
        node_feats, wh + OFF_IN, wl + OFF_IN, b_in, x, M, INDIM, Dd, 0);

    for (int l = 0; l < Ll; l++) {
        gemm_mfma128<<<dim3(768 / 128, M / 128), 256, 0, stream>>>(
            x, wh + OFF_QKV + (size_t)l * 196608, wl + OFF_QKV + (size_t)l * 196608,
            bqkv + l * 768, qkvb, M, Dd, 768, 0);
        attn_kernel<<<Bb * Hh * 4, 256, 0, stream>>>(
            qkvb, node_mask, offsets, elist, edge_index, edge_type, edge_weight, et_emb, attnout);
        gemm_mfma<<<dim3(Dd / 128, M / 64), 256, 0, stream>>>(
            attnout, wh + OFF_O + (size_t)l * 65536, wl + OFF_O + (size_t)l * 65536,
            bo + l * Dd, projb, M, Dd, Dd, 0);
        ln_kernel<<<M, 256, 0, stream>>>(x, projb, ln1_g + l * Dd, ln1_b + l * Dd);
        gemm_mfma128<<<dim3(FF / 128, M / 128), 256, 0, stream>>>(
            x, wh + OFF_F1 + (size_t)l * 262144, wl + OFF_F1 + (size_t)l * 262144,
            bff1 + l * FF, ffb, M, Dd, FF, 1);
        gemm_mfma<<<dim3(Dd / 128, M / 64), 256, 0, stream>>>(
            ffb, wh + OFF_F2 + (size_t)l * 262144, wl + OFF_F2 + (size_t)l * 262144,
            bff2 + l * Dd, projb, M, FF, Dd, 0);
        ln_kernel<<<M, 256, 0, stream>>>(x, projb, ln2_g + l * Dd, ln2_b + l * Dd);
    }

    pool_kernel<<<dim3(16, Bb), 256, 0, stream>>>(x, text_mask, image_mask, pools);
    comb_kernel<<<Bb, 256, 0, stream>>>(x, pools, gidx, comb);
    h1_kernel<<<dim3(4, Bb), 256, 0, stream>>>(comb, Wm1, bm1, h1);
    head_fin<<<Bb, 256, 0, stream>>>(h1, Wm2, bm2, Wm3, bm3, (float*)d_out);
}

// Round 11
// 691.939 us; speedup vs baseline: 2.0948x; 1.0189x over previous
//
#include <hip/hip_runtime.h>
#include <hip/hip_bf16.h>
#include <math.h>

#define Bb 16
#define Nn 512
#define Dd 256
#define Hh 8
#define HD 32
#define Ll 3
#define INDIM 768
#define Ee 4096
#define FF 1024
#define KP 40    // gemm LDS k-pitch in shorts (32 + 8 pad)

typedef unsigned short u16;
typedef __bf16 bf16x8 __attribute__((ext_vector_type(8)));
typedef float f32x4 __attribute__((ext_vector_type(4)));
typedef u16 us8 __attribute__((ext_vector_type(8)));
typedef u16 us4 __attribute__((ext_vector_type(4)));

__device__ __forceinline__ float gelu_exact(float x) {
    return 0.5f * x * (1.0f + erff(x * 0.70710678118654752f));
}

__device__ __forceinline__ u16 f2bf(float x) {
    unsigned int u = __float_as_uint(x);
    return (u16)((u + 0x7FFFu + ((u >> 16) & 1u)) >> 16);
}
__device__ __forceinline__ float bf2f(u16 h) {
    return __uint_as_float(((unsigned int)h) << 16);
}

// ---------------- edge bucketing ----------------

__global__ __launch_bounds__(256) void zero_kernel(int* __restrict__ p, int n) {
    int gid = blockIdx.x * 256 + threadIdx.x;
    if (gid < n) p[gid] = 0;
}

__global__ __launch_bounds__(256) void count_kernel(const int* __restrict__ edge_index,
                                                    int* __restrict__ counts) {
    int gid = blockIdx.x * 256 + threadIdx.x; // B*E = 65536
    int b = gid >> 12;
    int e = gid & (Ee - 1);
    int src = edge_index[b * 2 * Ee + e];
    atomicAdd(&counts[b * Nn + src], 1);
}

__global__ __launch_bounds__(1024) void scan_kernel(const int* __restrict__ counts,
                                                    int* __restrict__ offsets,
                                                    int* __restrict__ cursor) {
    __shared__ int ssum[1024];
    int t = threadIdx.x;
    int local[8];
    int s = 0;
#pragma unroll
    for (int i = 0; i < 8; i++) { local[i] = counts[t * 8 + i]; s += local[i]; }
    ssum[t] = s;
    __syncthreads();
    for (int off = 1; off < 1024; off *= 2) {
        __syncthreads();
        int v = (t >= off) ? ssum[t - off] : 0;
        __syncthreads();
        ssum[t] += v;
    }
    __syncthreads();
    int base = (t > 0) ? ssum[t - 1] : 0;
#pragma unroll
    for (int i = 0; i < 8; i++) {
        offsets[t * 8 + i] = base;
        cursor[t * 8 + i] = base;
        base += local[i];
    }
    if (t == 1023) offsets[8192] = base;
}

__global__ __launch_bounds__(256) void scatter_kernel(const int* __restrict__ edge_index,
                                                      int* __restrict__ cursor,
                                                      int* __restrict__ elist) {
    int gid = blockIdx.x * 256 + threadIdx.x;
    int b = gid >> 12;
    int e = gid & (Ee - 1);
    int src = edge_index[b * 2 * Ee + e];
    int pos = atomicAdd(&cursor[b * Nn + src], 1);
    elist[pos] = gid;
}

// ---------------- weight split+transpose: W[K][N] fp32 -> Wh,Wl [N][K] bf16 ----------------

__global__ __launch_bounds__(256) void wsplit(const float* __restrict__ W,
                                              u16* __restrict__ Wh,
                                              u16* __restrict__ Wl,
                                              int K, int N) {
    size_t moff = (size_t)blockIdx.z * K * N;
    const float* Ws = W + moff;
    u16* Whs = Wh + moff;
    u16* Wls = Wl + moff;
    int n = blockIdx.x * 256 + threadIdx.x;
    int k0 = blockIdx.y * 8;
    float w[8];
#pragma unroll
    for (int i = 0; i < 8; i++) w[i] = Ws[(size_t)(k0 + i) * N + n];
    u16 h[8], l[8];
#pragma unroll
    for (int i = 0; i < 8; i++) {
        h[i] = f2bf(w[i]);
        l[i] = f2bf(w[i] - bf2f(h[i]));
    }
    us8 hv = {h[0], h[1], h[2], h[3], h[4], h[5], h[6], h[7]};
    us8 lv = {l[0], l[1], l[2], l[3], l[4], l[5], l[6], l[7]};
    *(us8*)&Whs[(size_t)n * K + k0] = hv;
    *(us8*)&Wls[(size_t)n * K + k0] = lv;
}

// ---------------- MFMA GEMM 64x64 (bf16x3) — N=256 shapes: grid 512 = 2 blocks/CU -----
// 4 waves in 2x2, wave tile 32x32 (2x2 MFMA tiles): 12 mfma / 8 b128 reads per k-step.

__global__ __launch_bounds__(256) void gemm_mfma64(const float* __restrict__ A,
                                                   const u16* __restrict__ Bh,
                                                   const u16* __restrict__ Bl,
                                                   const float* __restrict__ bias,
                                                   float* __restrict__ C,
                                                   int M, int K, int N, int act) {
    __shared__ u16 sAh[64 * KP];
    __shared__ u16 sAl[64 * KP];
    __shared__ u16 sBh[64 * KP];
    __shared__ u16 sBl[64 * KP];

    int t = threadIdx.x;
    int w = t >> 6, L = t & 63;
    int wr = w >> 1, wc = w & 1;
    int lane15 = L & 15, quad = L >> 4;
    int row0 = blockIdx.y * 64, col0 = blockIdx.x * 64;

    f32x4 acc[2][2];
#pragma unroll
    for (int mi = 0; mi < 2; mi++)
#pragma unroll
        for (int ni = 0; ni < 2; ni++) acc[mi][ni] = {0.f, 0.f, 0.f, 0.f};

    int ar0 = t >> 3, akq0 = (t & 7) * 4;   // A: 2 units (rows ar0, ar0+32)
    int bn0 = t >> 2, bk0 = (t & 3) * 8;    // B: 1 unit

    const float* Ap0 = &A[(size_t)(row0 + ar0) * K + akq0];
    const float* Ap1 = &A[(size_t)(row0 + ar0 + 32) * K + akq0];
    const u16* Bhp = &Bh[(size_t)(col0 + bn0) * K + bk0];
    const u16* Blp = &Bl[(size_t)(col0 + bn0) * K + bk0];

    float4 av0 = *(const float4*)&Ap0[0];
    float4 av1 = *(const float4*)&Ap1[0];
    us8 bhv = *(const us8*)&Bhp[0];
    us8 blv = *(const us8*)&Blp[0];

    for (int k0 = 0; k0 < K; k0 += 32) {
        __syncthreads();
        {
            float a[4] = {av0.x, av0.y, av0.z, av0.w};
            u16 h[4], l[4];
#pragma unroll
            for (int i = 0; i < 4; i++) { h[i] = f2bf(a[i]); l[i] = f2bf(a[i] - bf2f(h[i])); }
            us4 hv = {h[0], h[1], h[2], h[3]};
            us4 lv = {l[0], l[1], l[2], l[3]};
            *(us4*)&sAh[ar0 * KP + akq0] = hv;
            *(us4*)&sAl[ar0 * KP + akq0] = lv;
        }
        {
            float a[4] = {av1.x, av1.y, av1.z, av1.w};
            u16 h[4], l[4];
#pragma unroll
            for (int i = 0; i < 4; i++) { h[i] = f2bf(a[i]); l[i] = f2bf(a[i] - bf2f(h[i])); }
            us4 hv = {h[0], h[1], h[2], h[3]};
            us4 lv = {l[0], l[1], l[2], l[3]};
            *(us4*)&sAh[(ar0 + 32) * KP + akq0] = hv;
            *(us4*)&sAl[(ar0 + 32) * KP + akq0] = lv;
        }
        *(us8*)&sBh[bn0 * KP + bk0] = bhv;
        *(us8*)&sBl[bn0 * KP + bk0] = blv;
        __syncthreads();

        if (k0 + 32 < K) {
            av0 = *(const float4*)&Ap0[k0 + 32];
            av1 = *(const float4*)&Ap1[k0 + 32];
            bhv = *(const us8*)&Bhp[k0 + 32];
            blv = *(const us8*)&Blp[k0 + 32];
        }

        us8 ahr[2], alr[2], bhr[2], blr[2];
#pragma unroll
        for (int mi = 0; mi < 2; mi++) {
            int ro = (wr * 32 + mi * 16 + lane15) * KP + quad * 8;
            ahr[mi] = *(const us8*)&sAh[ro];
            alr[mi] = *(const us8*)&sAl[ro];
        }
#pragma unroll
        for (int ni = 0; ni < 2; ni++) {
            int ro = (wc * 32 + ni * 16 + lane15) * KP + quad * 8;
            bhr[ni] = *(const us8*)&sBh[ro];
            blr[ni] = *(const us8*)&sBl[ro];
        }
#pragma unroll
        for (int mi = 0; mi < 2; mi++) {
            bf16x8 ah = *(const bf16x8*)&ahr[mi];
            bf16x8 al = *(const bf16x8*)&alr[mi];
#pragma unroll
            for (int ni = 0; ni < 2; ni++) {
                bf16x8 bh = *(const bf16x8*)&bhr[ni];
                bf16x8 bl = *(const bf16x8*)&blr[ni];
                acc[mi][ni] = __builtin_amdgcn_mfma_f32_16x16x32_bf16(ah, bh, acc[mi][ni], 0, 0, 0);
                acc[mi][ni] = __builtin_amdgcn_mfma_f32_16x16x32_bf16(ah, bl, acc[mi][ni], 0, 0, 0);
                acc[mi][ni] = __builtin_amdgcn_mfma_f32_16x16x32_bf16(al, bh, acc[mi][ni], 0, 0, 0);
            }
        }
    }

#pragma unroll
    for (int mi = 0; mi < 2; mi++) {
#pragma unroll
        for (int ni = 0; ni < 2; ni++) {
            int col = col0 + wc * 32 + ni * 16 + lane15;
            float bcol = bias[col];
#pragma unroll
            for (int r = 0; r < 4; r++) {
                int row = row0 + wr * 32 + mi * 16 + quad * 4 + r;
                float u = acc[mi][ni][r] + bcol;
                if (act == 1) u = gelu_exact(u);
                C[(size_t)row * N + col] = u;
            }
        }
    }
}

// ---------------- MFMA GEMM 128x128 (bf16x3), wave tile 64x64 — for N>=768 shapes -----

__global__ __launch_bounds__(256) void gemm_mfma128(const float* __restrict__ A,
                                                    const u16* __restrict__ Bh,
                                                    const u16* __restrict__ Bl,
                                                    const float* __restrict__ bias,
                                                    float* __restrict__ C,
                                                    int M, int K, int N, int act) {
    __shared__ u16 sAh[128 * KP];
    __shared__ u16 sAl[128 * KP];
    __shared__ u16 sBh[128 * KP];
    __shared__ u16 sBl[128 * KP];

    int t = threadIdx.x;
    int w = t >> 6, L = t & 63;
    int wr = w >> 1, wc = w & 1;
    int lane15 = L & 15, quad = L >> 4;
    int row0 = blockIdx.y * 128, col0 = blockIdx.x * 128;

    f32x4 acc[4][4];
#pragma unroll
    for (int mi = 0; mi < 4; mi++)
#pragma unroll
        for (int ni = 0; ni < 4; ni++) acc[mi][ni] = {0.f, 0.f, 0.f, 0.f};

    int ar0 = t >> 3, ak0 = (t & 7) * 4;
    int bn0 = t >> 2, bk0 = (t & 3) * 8;

    const float* Ap = &A[(size_t)(row0 + ar0) * K + ak0];
    const u16* Bhp = &Bh[(size_t)(col0 + bn0) * K + bk0];
    const u16* Blp = &Bl[(size_t)(col0 + bn0) * K + bk0];

    float4 av[4];
    us8 bhv[2], blv[2];
#pragma unroll
    for (int i = 0; i < 4; i++) av[i] = *(const float4*)&Ap[(size_t)(32 * i) * K];
#pragma unroll
    for (int i = 0; i < 2; i++) {
        bhv[i] = *(const us8*)&Bhp[(size_t)(64 * i) * K];
        blv[i] = *(const us8*)&Blp[(size_t)(64 * i) * K];
    }

    for (int k0 = 0; k0 < K; k0 += 32) {
        __syncthreads();
#pragma unroll
        for (int i = 0; i < 4; i++) {
            float a[4] = {av[i].x, av[i].y, av[i].z, av[i].w};
            u16 h[4], l[4];
#pragma unroll
            for (int j = 0; j < 4; j++) { h[j] = f2bf(a[j]); l[j] = f2bf(a[j] - bf2f(h[j])); }
            us4 hv = {h[0], h[1], h[2], h[3]};
            us4 lv = {l[0], l[1], l[2], l[3]};
            *(us4*)&sAh[(ar0 + 32 * i) * KP + ak0] = hv;
            *(us4*)&sAl[(ar0 + 32 * i) * KP + ak0] = lv;
        }
#pragma unroll
        for (int i = 0; i < 2; i++) {
            *(us8*)&sBh[(bn0 + 64 * i) * KP + bk0] = bhv[i];
            *(us8*)&sBl[(bn0 + 64 * i) * KP + bk0] = blv[i];
        }
        __syncthreads();

        if (k0 + 32 < K) {
#pragma unroll
            for (int i = 0; i < 4; i++) av[i] = *(const float4*)&Ap[(size_t)(32 * i) * K + k0 + 32];
#pragma unroll
            for (int i = 0; i < 2; i++) {
                bhv[i] = *(const us8*)&Bhp[(size_t)(64 * i) * K + k0 + 32];
                blv[i] = *(const us8*)&Blp[(size_t)(64 * i) * K + k0 + 32];
            }
        }

        us8 ahr[4], alr[4], bhr[4], blr[4];
#pragma unroll
        for (int mi = 0; mi < 4; mi++) {
            int ro = (wr * 64 + mi * 16 + lane15) * KP + quad * 8;
            ahr[mi] = *(const us8*)&sAh[ro];
            alr[mi] = *(const us8*)&sAl[ro];
        }
#pragma unroll
        for (int ni = 0; ni < 4; ni++) {
            int ro = (wc * 64 + ni * 16 + lane15) * KP + quad * 8;
            bhr[ni] = *(const us8*)&sBh[ro];
            blr[ni] = *(const us8*)&sBl[ro];
        }
#pragma unroll
        for (int mi = 0; mi < 4; mi++) {
            bf16x8 ah = *(const bf16x8*)&ahr[mi];
            bf16x8 al = *(const bf16x8*)&alr[mi];
#pragma unroll
            for (int ni = 0; ni < 4; ni++) {
                bf16x8 bh = *(const bf16x8*)&bhr[ni];
                bf16x8 bl = *(const bf16x8*)&blr[ni];
                acc[mi][ni] = __builtin_amdgcn_mfma_f32_16x16x32_bf16(ah, bh, acc[mi][ni], 0, 0, 0);
                acc[mi][ni] = __builtin_amdgcn_mfma_f32_16x16x32_bf16(ah, bl, acc[mi][ni], 0, 0, 0);
                acc[mi][ni] = __builtin_amdgcn_mfma_f32_16x16x32_bf16(al, bh, acc[mi][ni], 0, 0, 0);
            }
        }
    }

#pragma unroll
    for (int mi = 0; mi < 4; mi++) {
#pragma unroll
        for (int ni = 0; ni < 4; ni++) {
            int col = col0 + wc * 64 + ni * 16 + lane15;
            float bcol = bias[col];
#pragma unroll
            for (int r = 0; r < 4; r++) {
                int row = row0 + wr * 64 + mi * 16 + quad * 4 + r;
                float u = acc[mi][ni][r] + bcol;
                if (act == 1) u = gelu_exact(u);
                C[(size_t)row * N + col] = u;
            }
        }
    }
}

// ---------------- attention v7: flash MFMA + K/V register prefetch ----------------

#define SBP 132  // S-buffer / VT pitch (== 4 mod 32)

__global__ __launch_bounds__(256, 2) void attn_kernel(const float* __restrict__ qkv,
                                                      const int* __restrict__ node_mask,
                                                      const int* __restrict__ offsets,
                                                      const int* __restrict__ elist,
                                                      const int* __restrict__ edge_index,
                                                      const int* __restrict__ edge_type,
                                                      const float* __restrict__ edge_weight,
                                                      const float* __restrict__ et_emb,
                                                      float* __restrict__ outbuf) {
    int bid = blockIdx.x;            // b*32 + h*4 + quarter
    int quarter = bid & 3;
    int h = (bid >> 2) & 7;
    int b = bid >> 5;
    int t = threadIdx.x;
    int w = t >> 6, L = t & 63;
    int quad = L >> 4, lane15 = L & 15;
    int q8 = quad * 8;

    __shared__ u16 sKh[128 * 40];
    __shared__ u16 sKl[128 * 40];
    __shared__ u16 sVh[32 * SBP];
    __shared__ u16 sVl[32 * SBP];
    __shared__ float sS[4 * 16 * SBP];

    float* Sw = &sS[w * 16 * SBP];
    const float scale = 0.17677669529663687f;
    int nbase = quarter * 128 + w * 32;

    // staging geometry: thread handles (m = mt0 + 8j, d = dt), j = 0..15
    int mt0 = t >> 5, dt = t & 31;

    us8 Qh[2], Ql[2];
#pragma unroll
    for (int sub = 0; sub < 2; sub++) {
        size_t row = (size_t)(b * Nn + nbase + sub * 16 + lane15);
        float4 qa = *(const float4*)&qkv[row * 768 + h * HD + q8];
        float4 qb = *(const float4*)&qkv[row * 768 + h * HD + q8 + 4];
        float qv[8] = {qa.x, qa.y, qa.z, qa.w, qb.x, qb.y, qb.z, qb.w};
#pragma unroll
        for (int j = 0; j < 8; j++) {
            float xq = qv[j] * scale;
            u16 hh = f2bf(xq);
            Qh[sub][j] = hh;
            Ql[sub][j] = f2bf(xq - bf2f(hh));
        }
    }

    float Mst[2] = {-INFINITY, -INFINITY};
    float Lst[2] = {0.0f, 0.0f};
    f32x4 O[2][2];
#pragma unroll
    for (int sub = 0; sub < 2; sub++)
#pragma unroll
        for (int dc = 0; dc < 2; dc++) O[sub][dc] = {0.f, 0.f, 0.f, 0.f};

    // prefetch tile 0 K/V into registers
    float pk[16], pv[16];
#pragma unroll
    for (int j = 0; j < 16; j++) {
        size_t grow = (size_t)(b * Nn + mt0 + 8 * j) * 768 + h * HD + dt;
        pk[j] = qkv[grow + 256];
        pv[j] = qkv[grow + 512];
    }

    for (int T = 0; T < 4; T++) {
        int m0 = T * 128;
        __syncthreads();  // prior tile's LDS reads complete
        // convert + store prefetched K/V
#pragma unroll
        for (int j = 0; j < 16; j++) {
            int m = mt0 + 8 * j;
            u16 kh = f2bf(pk[j]);
            sKh[m * 40 + dt] = kh;
            sKl[m * 40 + dt] = f2bf(pk[j] - bf2f(kh));
            u16 vh = f2bf(pv[j]);
            sVh[dt * SBP + m] = vh;
            sVl[dt * SBP + m] = f2bf(pv[j] - bf2f(vh));
        }
        __syncthreads();
        // prefetch next tile (overlaps with this tile's compute)
        if (T < 3) {
#pragma unroll
            for (int j = 0; j < 16; j++) {
                size_t grow = (size_t)(b * Nn + (T + 1) * 128 + mt0 + 8 * j) * 768 + h * HD + dt;
                pk[j] = qkv[grow + 256];
                pv[j] = qkv[grow + 512];
            }
        }

        float mk[4][8];
#pragma unroll
        for (int c = 0; c < 4; c++) {
            int4 u0 = *(const int4*)&node_mask[b * Nn + m0 + c * 32 + q8];
            int4 u1 = *(const int4*)&node_mask[b * Nn + m0 + c * 32 + q8 + 4];
            mk[c][0] = u0.x ? 0.f : -INFINITY;
            mk[c][1] = u0.y ? 0.f : -INFINITY;
            mk[c][2] = u0.z ? 0.f : -INFINITY;
            mk[c][3] = u0.w ? 0.f : -INFINITY;
            mk[c][4] = u1.x ? 0.f : -INFINITY;
            mk[c][5] = u1.y ? 0.f : -INFINITY;
            mk[c][6] = u1.z ? 0.f : -INFINITY;
            mk[c][7] = u1.w ? 0.f : -INFINITY;
        }

#pragma unroll
        for (int sub = 0; sub < 2; sub++) {
            int nsub = nbase + sub * 16;
            bf16x8 qh = *(const bf16x8*)&Qh[sub];
            bf16x8 ql = *(const bf16x8*)&Ql[sub];

            f32x4 accS[8];
#pragma unroll
            for (int mc = 0; mc < 8; mc++) accS[mc] = {0.f, 0.f, 0.f, 0.f};
#pragma unroll
            for (int mc = 0; mc < 8; mc++) {
                us8 khr = *(const us8*)&sKh[(mc * 16 + lane15) * 40 + q8];
                us8 klr = *(const us8*)&sKl[(mc * 16 + lane15) * 40 + q8];
                bf16x8 kh = *(const bf16x8*)&khr;
                bf16x8 kl = *(const bf16x8*)&klr;
                accS[mc] = __builtin_amdgcn_mfma_f32_16x16x32_bf16(qh, kh, accS[mc], 0, 0, 0);
                accS[mc] = __builtin_amdgcn_mfma_f32_16x16x32_bf16(qh, kl, accS[mc], 0, 0, 0);
                accS[mc] = __builtin_amdgcn_mfma_f32_16x16x32_bf16(ql, kh, accS[mc], 0, 0, 0);
            }
#pragma unroll
            for (int mc = 0; mc < 8; mc++)
#pragma unroll
                for (int r = 0; r < 4; r++)
                    Sw[(quad * 4 + r) * SBP + mc * 16 + lane15] = accS[mc][r];
            asm volatile("s_waitcnt lgkmcnt(0)" ::: "memory");

            int beg = offsets[b * Nn + nsub];
            int end = offsets[b * Nn + nsub + 16];
            for (int i = beg + L; i < end; i += 64) {
                int ge = elist[i];
                int e = ge & (Ee - 1);
                int dst = edge_index[b * 2 * Ee + Ee + e];
                if (dst >= m0 && dst < m0 + 128) {
                    int src = edge_index[b * 2 * Ee + e];
                    int ty = edge_type[b * Ee + e];
                    float wgt = edge_weight[b * Ee + e];
                    float val = et_emb[ty * Hh + h] + (ty == 2 ? wgt : 0.0f);
                    atomicAdd(&Sw[(src - nsub) * SBP + (dst - m0)], val);
                }
            }
            asm volatile("s_waitcnt lgkmcnt(0)" ::: "memory");

            float s[4][8];
#pragma unroll
            for (int c = 0; c < 4; c++) {
                float4 a = *(const float4*)&Sw[lane15 * SBP + c * 32 + q8];
                float4 bq = *(const float4*)&Sw[lane15 * SBP + c * 32 + q8 + 4];
                s[c][0] = a.x + mk[c][0];  s[c][1] = a.y + mk[c][1];
                s[c][2] = a.z + mk[c][2];  s[c][3] = a.w + mk[c][3];
                s[c][4] = bq.x + mk[c][4]; s[c][5] = bq.y + mk[c][5];
                s[c][6] = bq.z + mk[c][6]; s[c][7] = bq.w + mk[c][7];
            }
            float mx = s[0][0];
#pragma unroll
            for (int c = 0; c < 4; c++)
#pragma unroll
                for (int j = 0; j < 8; j++) mx = fmaxf(mx, s[c][j]);
            mx = fmaxf(mx, __shfl_xor(mx, 16));
            mx = fmaxf(mx, __shfl_xor(mx, 32));
            float Mnew = fmaxf(Mst[sub], mx);
            float alpha = __expf(Mst[sub] - Mnew);
            float rs = 0.0f;
#pragma unroll
            for (int c = 0; c < 4; c++)
#pragma unroll
                for (int j = 0; j < 8; j++) {
                    s[c][j] = __expf(s[c][j] - Mnew);
                    rs += s[c][j];
                }
            rs += __shfl_xor(rs, 16);
            rs += __shfl_xor(rs, 32);
            Lst[sub] = Lst[sub] * alpha + rs;
            Mst[sub] = Mnew;

            us8 Ph[4], Pl[4];
#pragma unroll
            for (int c = 0; c < 4; c++)
#pragma unroll
                for (int j = 0; j < 8; j++) {
                    u16 ph = f2bf(s[c][j]);
                    Ph[c][j] = ph;
                    Pl[c][j] = f2bf(s[c][j] - bf2f(ph));
                }

            float aD[4];
#pragma unroll
            for (int r = 0; r < 4; r++) aD[r] = __shfl(alpha, (L & 48) | (quad * 4 + r));
#pragma unroll
            for (int dc = 0; dc < 2; dc++)
#pragma unroll
                for (int r = 0; r < 4; r++) O[sub][dc][r] *= aD[r];

#pragma unroll
            for (int c = 0; c < 4; c++) {
                bf16x8 ph = *(const bf16x8*)&Ph[c];
                bf16x8 pl = *(const bf16x8*)&Pl[c];
#pragma unroll
                for (int dc = 0; dc < 2; dc++) {
                    us8 vhr = *(const us8*)&sVh[(dc * 16 + lane15) * SBP + c * 32 + q8];
                    us8 vlr = *(const us8*)&sVl[(dc * 16 + lane15) * SBP + c * 32 + q8];
                    bf16x8 vh = *(const bf16x8*)&vhr;
                    bf16x8 vl = *(const bf16x8*)&vlr;
                    O[sub][dc] = __builtin_amdgcn_mfma_f32_16x16x32_bf16(ph, vh, O[sub][dc], 0, 0, 0);
                    O[sub][dc] = __builtin_amdgcn_mfma_f32_16x16x32_bf16(ph, vl, O[sub][dc], 0, 0, 0);
                    O[sub][dc] = __builtin_amdgcn_mfma_f32_16x16x32_bf16(pl, vh, O[sub][dc], 0, 0, 0);
                }
            }
        }
    }

#pragma unroll
    for (int sub = 0; sub < 2; sub++) {
        float linv = 1.0f / Lst[sub];
        float lD[4];
#pragma unroll
        for (int r = 0; r < 4; r++) lD[r] = __shfl(linv, (L & 48) | (quad * 4 + r));
#pragma unroll
        for (int dc = 0; dc < 2; dc++)
#pragma unroll
            for (int r = 0; r < 4; r++) {
                int row = nbase + sub * 16 + quad * 4 + r;
                outbuf[(size_t)(b * Nn + row) * Dd + h * HD + dc * 16 + lane15] =
                    O[sub][dc][r] * lD[r];
            }
    }
}

// ---------------- residual + LayerNorm ----------------

__global__ __launch_bounds__(256) void ln_kernel(float* __restrict__ x,
                                                 const float* __restrict__ res,
                                                 const float* __restrict__ g,
                                                 const float* __restrict__ bta) {
    int row = blockIdx.x;
    int t = threadIdx.x;
    __shared__ float red[4];
    __shared__ float stats[2];
    size_t idx = (size_t)row * Dd + t;
    float v = x[idx] + res[idx];
    float sm = v;
    for (int o = 32; o > 0; o >>= 1) sm += __shfl_down(sm, o);
    if ((t & 63) == 0) red[t >> 6] = sm;
    __syncthreads();
    if (t == 0) stats[0] = (red[0] + red[1] + red[2] + red[3]) * (1.0f / Dd);
    __syncthreads();
    float mu = stats[0];
    float dv = v - mu;
    float s2 = dv * dv;
    for (int o = 32; o > 0; o >>= 1) s2 += __shfl_down(s2, o);
    if ((t & 63) == 0) red[t >> 6] = s2;
    __syncthreads();
    if (t == 0) stats[1] = 1.0f / sqrtf((red[0] + red[1] + red[2] + red[3]) * (1.0f / Dd) + 1e-5f);
    __syncthreads();
    x[idx] = dv * stats[1] * g[t] + bta[t];
}

// ---------------- head ----------------

__global__ __launch_bounds__(256) void pool_kernel(const float* __restrict__ x,
                                                   const int* __restrict__ text_mask,
                                                   const int* __restrict__ image_mask,
                                                   float* __restrict__ pools) {
    int b = blockIdx.y;
    int n0 = blockIdx.x * 32;
    int t = threadIdx.x;
    float tp = 0.0f, ip = 0.0f, c1 = 0.0f, c2 = 0.0f;
    for (int n = n0; n < n0 + 32; n++) {
        float xv = x[(size_t)(b * Nn + n) * Dd + t];
        int tm = text_mask[b * Nn + n];
        int im = image_mask[b * Nn + n];
        tp += tm ? xv : 0.0f;
        ip += im ? xv : 0.0f;
        c1 += (float)tm;
        c2 += (float)im;
    }
    atomicAdd(&pools[b * 514 + t], tp);
    atomicAdd(&pools[b * 514 + 256 + t], ip);
    if (t == 0) {
        atomicAdd(&pools[b * 514 + 512], c1);
        atomicAdd(&pools[b * 514 + 513], c2);
    }
}

__global__ __launch_bounds__(256) void comb_kernel(const float* __restrict__ x,
                                                   const float* __restrict__ pools,
                                                   const int* __restrict__ gidx,
                                                   float* __restrict__ comb) {
    int b = blockIdx.x;
    int t = threadIdx.x;
    __shared__ float redd[12];
    float tc = fmaxf(pools[b * 514 + 512], 1.0f);
    float ic = fmaxf(pools[b * 514 + 513], 1.0f);
    float tp = pools[b * 514 + t] / tc;
    float ip = pools[b * 514 + 256 + t] / ic;
    int gi = gidx[b];
    comb[b * 776 + t] = x[(size_t)(b * Nn + gi) * Dd + t];
    comb[b * 776 + 256 + t] = tp;
    comb[b * 776 + 512 + t] = ip;
    float dotv = tp * ip, n1v = tp * tp, n2v = ip * ip;
    for (int o = 32; o > 0; o >>= 1) {
        dotv += __shfl_down(dotv, o);
        n1v += __shfl_down(n1v, o);
        n2v += __shfl_down(n2v, o);
    }
    if ((t & 63) == 0) { redd[t >> 6] = dotv; redd[4 + (t >> 6)] = n1v; redd[8 + (t >> 6)] = n2v; }
    __syncthreads();
    if (t == 0) {
        float dd = redd[0] + redd[1] + redd[2] + redd[3];
        float a1 = fmaxf(sqrtf(redd[4] + redd[5] + redd[6] + redd[7]), 1e-6f);
        float a2 = fmaxf(sqrtf(redd[8] + redd[9] + redd[10] + redd[11]), 1e-6f);
        comb[b * 776 + 768] = 1.0f - dd / (a1 * a2);
    }
}

__global__ __launch_bounds__(256) void h1_kernel(const float* __restrict__ comb,
                                                 const float* __restrict__ Wm1,
                                                 const float* __restrict__ bm1,
                                                 float* __restrict__ h1) {
    int b = blockIdx.y;
    int jc = blockIdx.x;
    int t = threadIdx.x;
    __shared__ float scomb[776];
    __shared__ float partial[2][128];
    for (int i = t; i < 769; i += 256) scomb[i] = comb[b * 776 + i];
    __syncthreads();
    int j = jc * 128 + (t & 127);
    int kh = t >> 7;
    int kbeg = kh ? 384 : 0;
    int kend = kh ? 769 : 384;
    float acc = 0.0f;
#pragma unroll 8
    for (int k = kbeg; k < kend; k++) acc += scomb[k] * Wm1[k * 512 + j];
    partial[kh][t & 127] = acc;
    __syncthreads();
    if (t < 128) {
        float v = partial[0][t] + partial[1][t] + bm1[jc * 128 + t];
        h1[b * 512 + jc * 128 + t] = gelu_exact(v);
    }
}

__global__ __launch_bounds__(256) void head_fin(const float* __restrict__ h1,
                                                const float* __restrict__ Wm2,
                                                const float* __restrict__ bm2,
                                                const float* __restrict__ Wm3,
                                                const float* __restrict__ bm3,
                                                float* __restrict__ out) {
    int b = blockIdx.x;
    int t = threadIdx.x;
    __shared__ float h1s[512];
    __shared__ float red[4];
    for (int i = t; i < 512; i += 256) h1s[i] = h1[b * 512 + i];
    __syncthreads();
    float acc = bm2[t];
#pragma unroll 8
    for (int k = 0; k < 512; k++) acc += h1s[k] * Wm2[k * 256 + t];
    float h2 = gelu_exact(acc);
    float lv = h2 * Wm3[t];
    for (int o = 32; o > 0; o >>= 1) lv += __shfl_down(lv, o);
    if ((t & 63) == 0) red[t >> 6] = lv;
    __syncthreads();
    if (t == 0) out[b] = red[0] + red[1] + red[2] + red[3] + bm3[0];
}

// ---------------- launch ----------------

#define OFF_IN  0
#define OFF_QKV 196608
#define OFF_O   786432
#define OFF_F1  983040
#define OFF_F2  1769472
#define W_TOTAL 2555904

extern "C" void kernel_launch(void* const* d_in, const int* in_sizes, int n_in,
                              void* d_out, int out_size, void* d_ws, size_t ws_size,
                              hipStream_t stream) {
    const float* node_feats = (const float*)d_in[0];
    const int* node_mask = (const int*)d_in[1];
    const int* text_mask = (const int*)d_in[2];
    const int* image_mask = (const int*)d_in[3];
    const int* gidx = (const int*)d_in[4];
    const int* edge_index = (const int*)d_in[5];
    const int* edge_type = (const int*)d_in[6];
    const float* edge_weight = (const float*)d_in[7];
    const float* W_in = (const float*)d_in[8];
    const float* b_in = (const float*)d_in[9];
    const float* Wqkv = (const float*)d_in[10];
    const float* bqkv = (const float*)d_in[11];
    const float* Wo = (const float*)d_in[12];
    const float* bo = (const float*)d_in[13];
    const float* ln1_g = (const float*)d_in[14];
    const float* ln1_b = (const float*)d_in[15];
    const float* ln2_g = (const float*)d_in[16];
    const float* ln2_b = (const float*)d_in[17];
    const float* Wff1 = (const float*)d_in[18];
    const float* bff1 = (const float*)d_in[19];
    const float* Wff2 = (const float*)d_in[20];
    const float* bff2 = (const float*)d_in[21];
    const float* et_emb = (const float*)d_in[22];
    const float* Wm1 = (const float*)d_in[23];
    const float* bm1 = (const float*)d_in[24];
    const float* Wm2 = (const float*)d_in[25];
    const float* bm2 = (const float*)d_in[26];
    const float* Wm3 = (const float*)d_in[27];
    const float* bm3 = (const float*)d_in[28];

    const int M = Bb * Nn; // 8192
    char* ws = (char*)d_ws;
    size_t off = 0;
    auto alloc = [&](size_t bytes) {
        void* p = ws + off;
        off += (bytes + 255) & ~(size_t)255;
        return p;
    };
    float* x = (float*)alloc((size_t)M * Dd * 4);
    float* qkvb = (float*)alloc((size_t)M * FF * 4);
    float* ffb = qkvb;
    float* attnout = (float*)alloc((size_t)M * Dd * 4);
    float* projb = (float*)alloc((size_t)M * Dd * 4);
    int* counts = (int*)alloc(8192 * 4);
    int* offsets = (int*)alloc(8193 * 4);
    int* cursor = (int*)alloc(8192 * 4);
    int* elist = (int*)alloc((size_t)Bb * Ee * 4);
    float* pools = (float*)alloc((size_t)Bb * 514 * 4);
    float* comb = (float*)alloc((size_t)Bb * 776 * 4);
    float* h1 = (float*)alloc((size_t)Bb * 512 * 4);
    u16* wh = (u16*)alloc((size_t)W_TOTAL * 2);
    u16* wl = (u16*)alloc((size_t)W_TOTAL * 2);
    (void)ws_size;

    zero_kernel<<<32, 256, 0, stream>>>(counts, 8192);
    zero_kernel<<<(Bb * 514 + 255) / 256, 256, 0, stream>>>((int*)pools, Bb * 514);
    count_kernel<<<256, 256, 0, stream>>>(edge_index, counts);
    scan_kernel<<<1, 1024, 0, stream>>>(counts, offsets, cursor);
    scatter_kernel<<<256, 256, 0, stream>>>(edge_index, cursor, elist);

    wsplit<<<dim3(1, 96, 1), 256, 0, stream>>>(W_in, wh + OFF_IN, wl + OFF_IN, 768, 256);
    wsplit<<<dim3(3, 32, 3), 256, 0, stream>>>(Wqkv, wh + OFF_QKV, wl + OFF_QKV, 256, 768);
    wsplit<<<dim3(1, 32, 3), 256, 0, stream>>>(Wo, wh + OFF_O, wl + OFF_O, 256, 256);
    wsplit<<<dim3(4, 32, 3), 256, 0, stream>>>(Wff1, wh + OFF_F1, wl + OFF_F1, 256, 1024);
    wsplit<<<dim3(1, 128, 3), 256, 0, stream>>>(Wff2, wh + OFF_F2, wl + OFF_F2, 1024, 256);

    // N=256 GEMMs: 64x64 tiles -> 512 blocks (2/CU)
    gemm_mfma64<<<dim3(Dd / 64, M / 64), 256, 0, stream>>>(
        node_feats, wh + OFF_IN, wl + OFF_IN, b_in, x, M, INDIM, Dd, 0);

    for (int l = 0; l < Ll; l++) {
        gemm_mfma128<<<dim3(768 / 128, M / 128), 256, 0, stream>>>(
            x, wh + OFF_QKV + (size_t)l * 196608, wl + OFF_QKV + (size_t)l * 196608,
            bqkv + l * 768, qkvb, M, Dd, 768, 0);
        attn_kernel<<<Bb * Hh * 4, 256, 0, stream>>>(
            qkvb, node_mask, offsets, elist, edge_index, edge_type, edge_weight, et_emb, attnout);
        gemm_mfma64<<<dim3(Dd / 64, M / 64), 256, 0, stream>>>(
            attnout, wh + OFF_O + (size_t)l * 65536, wl + OFF_O + (size_t)l * 65536,
            bo + l * Dd, projb, M, Dd, Dd, 0);
        ln_kernel<<<M, 256, 0, stream>>>(x, projb, ln1_g + l * Dd, ln1_b + l * Dd);
        gemm_mfma128<<<dim3(FF / 128, M / 128), 256, 0, stream>>>(
            x, wh + OFF_F1 + (size_t)l * 262144, wl + OFF_F1 + (size_t)l * 262144,
            bff1 + l * FF, ffb, M, Dd, FF, 1);
        gemm_mfma64<<<dim3(Dd / 64, M / 64), 256, 0, stream>>>(
            ffb, wh + OFF_F2 + (size_t)l * 262144, wl + OFF_F2 + (size_t)l * 262144,
            bff2 + l * Dd, projb, M, FF, Dd, 0);
        ln_kernel<<<M, 256, 0, stream>>>(x, projb, ln2_g + l * Dd, ln2_b + l * Dd);
    }

    pool_kernel<<<dim3(16, Bb), 256, 0, stream>>>(x, text_mask, image_mask, pools);
    comb_kernel<<<Bb, 256, 0, stream>>>(x, pools, gidx, comb);
    h1_kernel<<<dim3(4, Bb), 256, 0, stream>>>(comb, Wm1, bm1, h1);
    head_fin<<<Bb, 256, 0, stream>>>(h1, Wm2, bm2, Wm3, bm3, (float*)d_out);
}